// Round 8
// baseline (631.198 us; speedup 1.0000x reference)
//
#include <hip/hip_runtime.h>

#define DI __device__ __forceinline__

static constexpr int NN = 20000;   // nodes
static constexpr int NE = 160000;  // edges

typedef __attribute__((ext_vector_type(4))) float f32x4;
typedef _Float16 f16x2 __attribute__((ext_vector_type(2)));
typedef _Float16 f16x8 __attribute__((ext_vector_type(8)));

DI float rl(float v, int lane) {
    return __int_as_float(__builtin_amdgcn_readlane(__float_as_int(v), lane));
}
DI float xr(float v, int m) { return __shfl_xor(v, m, 64); }
DI int xri(int v, int m) { return __shfl_xor(v, m, 64); }
DI float wsum64(float v) {
    v += xr(v, 1); v += xr(v, 2); v += xr(v, 4);
    v += xr(v, 8); v += xr(v, 16); v += xr(v, 32);
    return v;
}
DI int wsum64i(int v) {
    v += xri(v, 1); v += xri(v, 2); v += xri(v, 4);
    v += xri(v, 8); v += xri(v, 16); v += xri(v, 32);
    return v;
}
DI float hsum16(float v) {
    v += xr(v, 1); v += xr(v, 2); v += xr(v, 4); v += xr(v, 8);
    return v;
}
// DPP-based reductions: pure VALU, no LDS-pipe traffic.
DI float hsum16d(float v) {
    v += __int_as_float(__builtin_amdgcn_mov_dpp(__float_as_int(v), 0xB1, 0xF, 0xF, true));   // xor1
    v += __int_as_float(__builtin_amdgcn_mov_dpp(__float_as_int(v), 0x4E, 0xF, 0xF, true));   // xor2
    v += __int_as_float(__builtin_amdgcn_mov_dpp(__float_as_int(v), 0x141, 0xF, 0xF, true));  // half mirror
    v += __int_as_float(__builtin_amdgcn_mov_dpp(__float_as_int(v), 0x140, 0xF, 0xF, true));  // row mirror
    return v;
}
DI float wsum64v(float v) {
    v = hsum16d(v);
    return (rl(v, 0) + rl(v, 16)) + (rl(v, 32) + rl(v, 48));
}
DI unsigned short f2h(float x) {
    union { _Float16 f; unsigned short u; } c;
    c.f = (_Float16)x;
    return c.u;
}

// ================= prepA =================
// block ranges:
//   [0,1024)      prep_w   (memw_w -> fp16, layout [i][o][d])
//   [1024,1088)   prep_wov
//   1088          fused precomp+prep2 (P in LDS, all small tables out)
//   [1089,1714)   hist (etype block counts)
//   [1714,2964)   zero agg (float4 stores)
//   [2964,2984)   zero deg
__global__ __launch_bounds__(256) void prepA_kernel(
    const float* __restrict__ mw, unsigned short* __restrict__ Wstg,
    const float* __restrict__ in_w, const float* __restrict__ out_w,
    float* __restrict__ WOVg,
    const float* __restrict__ cls_w, const float* __restrict__ sep,
    const float* __restrict__ in_b,
    const int* __restrict__ et, int* __restrict__ bc,
    float* __restrict__ agg, float* __restrict__ deg,
    const float* __restrict__ mc_w, const float* __restrict__ mc_b,
    const float* __restrict__ ln1_g, const float* __restrict__ ln1_b,
    const float* __restrict__ ln2_g, const float* __restrict__ ln2_b,
    const float* __restrict__ ff1_w, const float* __restrict__ ff1_b,
    const float* __restrict__ out_b,
    float* __restrict__ SWg, float* __restrict__ SB16,
    float* __restrict__ OvcG, float* __restrict__ OvsG,
    float* __restrict__ bOvG, float* __restrict__ s0n,
    float* __restrict__ s2n, float* __restrict__ MC8,
    float* __restrict__ GcT, float* __restrict__ GsT,
    float* __restrict__ DCC, float* __restrict__ B0T,
    float* __restrict__ mgT) {
    int b = blockIdx.x, t = threadIdx.x;
    __shared__ int c[5];
    __shared__ float P[608];
    if (b < 1024) {                      // prep_w
        int idx = b * 256 + t;
        int d = idx & 63, o = (idx >> 6) & 63, i = idx >> 12;
        Wstg[idx] = f2h(mw[(o * 64 + i) * 64 + d]);
    } else if (b < 1088) {               // prep_wov
        int u = (b - 1024) * 256 + t;    // 16384
        int h = u & 3, l = (u >> 2) & 63, j = u >> 8;
        float acc = 0.f;
        for (int i = 0; i < 16; i++)
            acc += out_w[l * 64 + h * 16 + i] * in_w[(128 + h * 16 + i) * 64 + j];
        WOVg[u] = acc;
    } else if (b == 1088) {              // fused precomp + prep2
        if (t < 64) {                    // precomp into LDS P
            int l = t;
            float bq = in_b[l], bk = in_b[64 + l], bv = in_b[128 + l];
            float xs = sep[l];
            float ks = bk, vs = bv;
            for (int j = 0; j < 64; j++) {
                float xj = rl(xs, j);
                ks += in_w[(64 + l) * 64 + j] * xj;
                vs += in_w[(128 + l) * 64 + j] * xj;
            }
            P[512 + l] = vs;
            for (int m = 0; m < 4; m++) {
                float xc = cls_w[m * 64 + l];
                float q0 = bq, kc = bk, vc = bv;
                for (int j = 0; j < 64; j++) {
                    float xj = rl(xc, j);
                    q0 += in_w[l * 64 + j] * xj;
                    kc += in_w[(64 + l) * 64 + j] * xj;
                    vc += in_w[(128 + l) * 64 + j] * xj;
                }
                P[m * 64 + l] = q0;
                P[256 + m * 64 + l] = vc;
                float p0 = hsum16(q0 * kc);
                float p2 = hsum16(q0 * ks);
                if ((l & 15) == 0) {
                    P[576 + m * 4 + (l >> 4)] = p0 * 0.25f;
                    P[592 + m * 4 + (l >> 4)] = p2 * 0.25f;
                }
            }
        }
        __syncthreads();
        // prep2
        for (int u = t; u < 1024; u += 256) {       // SW
            int m = u >> 8, h = (u >> 6) & 3, j = u & 63;
            float acc = 0.f;
            for (int i = 0; i < 16; i++)
                acc += P[m * 64 + h * 16 + i] * in_w[(64 + h * 16 + i) * 64 + j];
            SWg[u] = 0.25f * acc;
        }
        for (int u = t; u < 1024; u += 256) {       // Ovc
            int h = u & 3, ll = (u >> 2) & 63, m = u >> 8;
            float acc = 0.f;
            for (int i = 0; i < 16; i++)
                acc += out_w[ll * 64 + h * 16 + i] * P[256 + m * 64 + h * 16 + i];
            OvcG[u] = acc;
        }
        if (t < 256) {                              // Ovs, bOv
            int h = t & 3, ll = t >> 2;
            float a1 = 0.f, a2 = 0.f;
            for (int i = 0; i < 16; i++) {
                a1 += out_w[ll * 64 + h * 16 + i] * P[512 + h * 16 + i];
                a2 += out_w[ll * 64 + h * 16 + i] * in_b[128 + h * 16 + i];
            }
            OvsG[t] = a1;
            bOvG[t] = a2;
        }
        if (t < 256) {                              // B0T, mgT
            B0T[t] = cls_w[t] + out_b[t & 63];
            int p = t >> 2, cc = t & 3;
            mgT[t] = mc_w[cc * 64 + p] * ln2_g[p];
        }
        if (t < 16) {                               // SB16, s0n, s2n
            int m = t >> 2, h = t & 3;
            float acc = 0.f;
            for (int i = 0; i < 16; i++)
                acc += P[m * 64 + h * 16 + i] * in_b[64 + h * 16 + i];
            SB16[t] = 0.25f * acc;
            s0n[t] = P[576 + t];
            s2n[t] = P[592 + t];
        }
        if (t < 8) {                                // Mc / Cc
            int cc = t & 3;
            float acc = 0.f;
            if (t < 4) {
                for (int ll = 0; ll < 64; ll++) acc += mc_w[cc * 64 + ll] * ln2_g[ll];
            } else {
                for (int ll = 0; ll < 64; ll++) acc += mc_w[cc * 64 + ll] * ln2_b[ll];
                acc += mc_b[cc];
            }
            MC8[t] = acc;
        }
        __syncthreads();   // block-level fence: OvcG/OvsG global writes visible
        if (t < 256) {                              // GcT
            int m = t >> 6, f = (t >> 2) & 15, h = t & 3;
            float acc = 0.f;
            for (int p = 0; p < 64; p++)
                acc += ff1_w[f * 64 + p] * ln1_g[p] * OvcG[(m * 64 + p) * 4 + h];
            GcT[t] = acc;
        }
        if (t < 64) {                               // GsT
            int f = t >> 2, h = t & 3;
            float acc = 0.f;
            for (int p = 0; p < 64; p++)
                acc += ff1_w[f * 64 + p] * ln1_g[p] * OvsG[p * 4 + h];
            GsT[t] = acc;
        }
        if (t < 64) {                               // DCC
            int m = t >> 4, f = t & 15;
            float d0 = 0.f, c1 = 0.f, c2 = 0.f;
            for (int p = 0; p < 64; p++) {
                float wv = ff1_w[f * 64 + p];
                d0 += wv * ln1_g[p] * (cls_w[m * 64 + p] + out_b[p]);
                c1 += wv * ln1_g[p];
                c2 += wv * ln1_b[p];
            }
            f32x4 r = {d0, c1, c2 + ff1_b[f], 0.f};
            ((f32x4*)DCC)[t] = r;
        }
    } else if (b < 1714) {               // hist
        int bb = b - 1089;
        if (t < 5) c[t] = 0;
        __syncthreads();
        int e = bb * 256 + t;
        atomicAdd(&c[et[e]], 1);
        __syncthreads();
        if (t < 5) bc[bb * 5 + t] = c[t];
    } else if (b < 2964) {               // zero agg (exact: 1250*256 f32x4)
        int idx = (b - 1714) * 256 + t;
        f32x4 z = {0.f, 0.f, 0.f, 0.f};
        ((f32x4*)agg)[idx] = z;
    } else {                             // zero deg (5000 f32x4)
        int idx = (b - 2964) * 256 + t;
        if (idx < 5000) {
            f32x4 z = {0.f, 0.f, 0.f, 0.f};
            ((f32x4*)deg)[idx] = z;
        }
    }
}

// ================= prepC: [rank(self-scan)+deg | node_pre] =================
// blocks [0,625) rank; [625,5625) node_pre
__global__ __launch_bounds__(256) void prepC_kernel(
    const int* __restrict__ et, const int* __restrict__ bc,
    const int* __restrict__ dstp, float* __restrict__ deg,
    int* __restrict__ rowbase, int* __restrict__ estride,
    const float* __restrict__ feat, const float* __restrict__ SWg,
    const float* __restrict__ SB16, const float* __restrict__ WOVg,
    const float* __restrict__ bOvG, const float* __restrict__ ff1_w,
    const float* __restrict__ ln1_g,
    float* __restrict__ Sout, float* __restrict__ Ovout, float* __restrict__ Gn) {
    __shared__ float SWs[1024];
    __shared__ f32x4 WOVs[4096];
    __shared__ __align__(16) float F1gL[1024];
    __shared__ __align__(16) float accT[4][4][64];
    __shared__ int wc[4][5];
    __shared__ int pre_s[5], tot_s[5], cs5[5];
    int tid = threadIdx.x;
    if (blockIdx.x < 625) {              // rank with self-scan + deg
        int b = blockIdx.x;
        if (tid < 5) { pre_s[tid] = 0; tot_s[tid] = 0; }
        __syncthreads();
#pragma unroll
        for (int ty = 0; ty < 5; ty++) {
            int pp = 0, tt = 0;
            for (int b2 = tid; b2 < 625; b2 += 256) {
                int v = bc[b2 * 5 + ty];
                tt += v;
                if (b2 < b) pp += v;
            }
            pp = wsum64i(pp);
            tt = wsum64i(tt);
            if ((tid & 63) == 0) {
                atomicAdd(&pre_s[ty], pp);
                atomicAdd(&tot_s[ty], tt);
            }
        }
        __syncthreads();
        if (tid == 0) {
            int s = 0;
            for (int e = 0; e < 5; e++) { cs5[e] = s; s += tot_s[e]; }
        }
        int w = tid >> 6, lane = tid & 63;
        int e = b * 256 + tid;           // always < NE (625*256 exact)
        int my = et[e];
        unsigned long long bal[5];
#pragma unroll
        for (int ty = 0; ty < 5; ty++) bal[ty] = __ballot(my == ty);
        if (lane == 0) {
#pragma unroll
            for (int ty = 0; ty < 5; ty++) wc[w][ty] = __popcll(bal[ty]);
        }
        __syncthreads();
        unsigned long long lt = ((unsigned long long)1 << lane) - 1;
        int intra = __popcll(bal[my] & lt);
        int pre = 0;
        for (int w2 = 0; w2 < w; w2++) pre += wc[w2][my];
        rowbase[e] = 4 * cs5[my] + pre_s[my] + pre + intra;
        estride[e] = tot_s[my];
        atomicAdd(&deg[dstp[e]], 1.0f);
        return;
    }
    // node_pre
    int nb4 = blockIdx.x - 625;
    for (int p = tid; p < 1024; p += 256) {
        SWs[p] = SWg[p];
        F1gL[p] = ff1_w[p] * ln1_g[p & 63];
    }
    for (int p = tid; p < 4096; p += 256) WOVs[p] = ((const f32x4*)WOVg)[p];
    __syncthreads();
    int w = tid >> 6, l = tid & 63;
    int n = nb4 * 4 + w;
    float f = feat[(size_t)n * 64 + l];
    f32x4 acc = ((const f32x4*)bOvG)[l];
#pragma unroll 8
    for (int j = 0; j < 64; j++) {
        float fj = rl(f, j);
        f32x4 wv = WOVs[j * 64 + l];
        acc += wv * fj;
    }
    ((f32x4*)Ovout)[(size_t)n * 64 + l] = acc;
    accT[w][0][l] = acc[0];
    accT[w][1][l] = acc[1];
    accT[w][2][l] = acc[2];
    accT[w][3][l] = acc[3];
#pragma unroll
    for (int mh = 0; mh < 16; mh++) {
        float v = SWs[mh * 64 + l] * f;
        v = wsum64v(v);
        if (l == mh) Sout[(size_t)n * 16 + mh] = v + SB16[mh];  // [m][h] layout
    }
    asm volatile("s_waitcnt lgkmcnt(0)" ::: "memory");
    int ff = l & 15, hh = l >> 4;
    float g = 0.f;
#pragma unroll
    for (int c2 = 0; c2 < 16; c2++) {
        int cc = (c2 + ff) & 15;  // stagger to avoid bank conflicts
        f32x4 wv = *(const f32x4*)&F1gL[ff * 64 + cc * 4];
        f32x4 av = *(const f32x4*)&accT[w][hh][cc * 4];
        g += wv[0] * av[0] + wv[1] * av[1] + wv[2] * av[2] + wv[3] * av[3];
    }
    Gn[(size_t)n * 64 + ff * 4 + hh] = g;
}

// ================= encoder (merged edges+nodes): slot-parallel =================
__global__ __launch_bounds__(256, 4) void enc_kernel(
    const int* __restrict__ src, const int* __restrict__ dst,
    const float* __restrict__ Sg, const float* __restrict__ Ovg,
    const float* __restrict__ Gn, const float* __restrict__ OvcG,
    const float* __restrict__ OvsG, const float* __restrict__ GcT,
    const float* __restrict__ GsT, const float* __restrict__ DCC,
    const float* __restrict__ B0T, const float* __restrict__ mgT,
    const float* __restrict__ s0n, const float* __restrict__ s2n,
    const float* __restrict__ MC8,
    const float* __restrict__ ln1_g, const float* __restrict__ ln1_b,
    const float* __restrict__ ln2_g, const float* __restrict__ ln2_b,
    const float* __restrict__ ff2_w, const float* __restrict__ ff2_b,
    const int* __restrict__ rowbase, const int* __restrict__ estride,
    float* __restrict__ mem_out, float* __restrict__ out_cat,
    float* __restrict__ out_label) {
    __shared__ __align__(16) float F2C[1024];   // F2C[f][p] = ff2_w[p][f]
    __shared__ __align__(16) float TBL[1704];   // 426 f32x4 of fused tables
    int tid = threadIdx.x;
    for (int p = tid; p < 1024; p += 256) F2C[(p & 15) * 64 + (p >> 4)] = ff2_w[p];
    {
        f32x4* T4w = (f32x4*)TBL;
        int i = tid;
        if (i < 64) {
            T4w[i]        = ((const f32x4*)B0T)[i];                         // [l]
            T4w[64 + i]   = ((const f32x4*)GcT)[i];                         // [l]
            T4w[128 + i]  = ((const f32x4*)DCC)[i];                         // [l]
            T4w[192 + (i & 3) * 16 + (i >> 2)] = ((const f32x4*)OvsG)[i];   // [k][u]
            T4w[256 + (i & 3) * 16 + (i >> 2)] = ((const f32x4*)mgT)[i];    // [k][u]
        }
        if (i < 16) {
            T4w[320 + i] = ((const f32x4*)GsT)[i];                          // [u]
            T4w[346 + i] = *(const f32x4*)(ln1_g + i * 4);                  // [u]
            T4w[362 + i] = *(const f32x4*)(ln1_b + i * 4);                  // [u]
            T4w[378 + i] = *(const f32x4*)(ln2_g + i * 4);                  // [u]
            T4w[394 + i] = *(const f32x4*)(ln2_b + i * 4);                  // [u]
            T4w[410 + i] = *(const f32x4*)(ff2_b + i * 4);                  // [u]
        }
        if (i < 4) {
            T4w[336 + i] = ((const f32x4*)s0n)[i];                          // [m]
            T4w[340 + i] = ((const f32x4*)s2n)[i];                          // [m]
        }
        if (i < 2) T4w[344 + i] = ((const f32x4*)MC8)[i];                   // Mc, Cc
    }
    __syncthreads();
    const f32x4* F2C4 = (const f32x4*)F2C;
    const f32x4* Sg4 = (const f32x4*)Sg;
    const f32x4* Og4 = (const f32x4*)Ovg;
    const f32x4* Gn4 = (const f32x4*)Gn;

    int l = tid & 63, m = l >> 4, u = l & 15;
    f32x4 OvcR0 = ((const f32x4*)OvcG)[m * 64 + u * 4 + 0];
    f32x4 OvcR1 = ((const f32x4*)OvcG)[m * 64 + u * 4 + 1];
    f32x4 OvcR2 = ((const f32x4*)OvcG)[m * 64 + u * 4 + 2];
    f32x4 OvcR3 = ((const f32x4*)OvcG)[m * 64 + u * 4 + 3];
    int ubase = u * 17;  // F2C f32x4 index for f=u, chunk=u
    int wid = blockIdx.x * 4 + (tid >> 6);
    int nw = gridDim.x * 4;

#pragma unroll 2
    for (int it = wid; it < NE + NN; it += nw) {
        int tb = 0;
        asm volatile("" : "+v"(tb));  // opaque zero: blocks LICM of LDS table reads
        const f32x4* T4 = ((const f32x4*)TBL) + tb;
        int itu = __builtin_amdgcn_readfirstlane(it);
        bool isE = itu < NE;
        int ia = isE ? src[itu] : (itu - NE);
        f32x4 SaV = Sg4[(size_t)ia * 4 + m];
        f32x4 GaV = Gn4[(size_t)ia * 16 + u];
        f32x4 OvaR0 = Og4[(size_t)ia * 64 + u * 4 + 0];
        f32x4 OvaR1 = Og4[(size_t)ia * 64 + u * 4 + 1];
        f32x4 OvaR2 = Og4[(size_t)ia * 64 + u * 4 + 2];
        f32x4 OvaR3 = Og4[(size_t)ia * 64 + u * 4 + 3];
        f32x4 SbV = SaV, GbV = GaV;
        f32x4 OvbR0 = OvaR0, OvbR1 = OvaR1, OvbR2 = OvaR2, OvbR3 = OvaR3;
        int rb = 0, st = 0;
        if (isE) {
            int ib = dst[itu];
            SbV = Sg4[(size_t)ib * 4 + m];
            GbV = Gn4[(size_t)ib * 16 + u];
            OvbR0 = Og4[(size_t)ib * 64 + u * 4 + 0];
            OvbR1 = Og4[(size_t)ib * 64 + u * 4 + 1];
            OvbR2 = Og4[(size_t)ib * 64 + u * 4 + 2];
            OvbR3 = Og4[(size_t)ib * 64 + u * 4 + 3];
            rb = rowbase[itu];
            st = estride[itu];
        }
        f32x4 s0v = T4[336 + m];
        f32x4 s2v = T4[340 + m];
        f32x4 B0v = T4[l];
        f32x4 GcV = T4[64 + l];
        f32x4 DCv = T4[128 + l];
        f32x4 GsV = T4[320 + u];
        f32x4 OvsR0 = T4[192 + u];
        f32x4 OvsR1 = T4[208 + u];
        f32x4 OvsR2 = T4[224 + u];
        f32x4 OvsR3 = T4[240 + u];

        // softmax over 4 tokens for all 4 heads
        f32x4 mx, e0, e1, e2, e3, w0v, w1v, w2v, w3v;
#pragma unroll
        for (int h = 0; h < 4; h++)
            mx[h] = fmaxf(fmaxf(s0v[h], SaV[h]), fmaxf(s2v[h], SbV[h]));
#pragma unroll
        for (int h = 0; h < 4; h++) {
            e0[h] = __expf(s0v[h] - mx[h]);
            e1[h] = __expf(SaV[h] - mx[h]);
            e2[h] = __expf(s2v[h] - mx[h]);
            e3[h] = __expf(SbV[h] - mx[h]);
        }
#pragma unroll
        for (int h = 0; h < 4; h++) {
            float inv = 1.f / (e0[h] + e1[h] + e2[h] + e3[h]);
            w0v[h] = e0[h] * inv; w1v[h] = e1[h] * inv;
            w2v[h] = e2[h] * inv; w3v[h] = e3[h] * inv;
        }
        // x build
        f32x4 xv = B0v;
#pragma unroll
        for (int h = 0; h < 4; h++) {
            float W0 = w0v[h], W1 = w1v[h], W2 = w2v[h], W3 = w3v[h];
            xv[0] += W0 * OvcR0[h] + W1 * OvaR0[h] + W2 * OvsR0[h] + W3 * OvbR0[h];
            xv[1] += W0 * OvcR1[h] + W1 * OvaR1[h] + W2 * OvsR1[h] + W3 * OvbR1[h];
            xv[2] += W0 * OvcR2[h] + W1 * OvaR2[h] + W2 * OvsR2[h] + W3 * OvbR2[h];
            xv[3] += W0 * OvcR3[h] + W1 * OvaR3[h] + W2 * OvsR3[h] + W3 * OvbR3[h];
        }
        // LN1 stats
        float sx = hsum16d(xv[0] + xv[1] + xv[2] + xv[3]);
        float sxx = hsum16d(xv[0] * xv[0] + xv[1] * xv[1] + xv[2] * xv[2] + xv[3] * xv[3]);
        float mu = sx * 0.015625f;
        float var = sxx * 0.015625f - mu * mu;
        float r1 = rsqrtf(var + 1e-5f);
        // FF1 via G-tables
        f32x4 av = w0v * GcV + w1v * GaV + w2v * GsV + w3v * GbV;
        float accF = av[0] + av[1] + av[2] + av[3] + DCv[0];
        float hp = r1 * accF - (r1 * mu) * DCv[1] + DCv[2];
        float hr = fmaxf(hp, 0.f);
        // LN1 apply, y = x1 + ff2_bias
        f32x4 g1r = T4[346 + u], b1r = T4[362 + u], f2br = T4[410 + u];
        xv = (xv - mu) * (g1r * r1) + b1r;
        f32x4 yv = xv + f2br;
        // FF2 gray-code XOR walk
        float hrot = hr;
        int a16 = ubase + tb;
        { f32x4 wv = F2C4[a16]; yv += wv * hrot; }
#define FSTEP(CTL, MSK)                                                                         \
        hrot = __int_as_float(__builtin_amdgcn_mov_dpp(__float_as_int(hrot), (CTL), 0xF, 0xF, true)); \
        a16 ^= (MSK) * 16;                                                                      \
        { f32x4 wv = F2C4[a16]; yv += wv * hrot; }
        FSTEP(0xB1, 1) FSTEP(0x4E, 2) FSTEP(0xB1, 1) FSTEP(0x141, 7)
        FSTEP(0xB1, 1) FSTEP(0x4E, 2) FSTEP(0xB1, 1) FSTEP(0x140, 15)
        FSTEP(0xB1, 1) FSTEP(0x4E, 2) FSTEP(0xB1, 1) FSTEP(0x141, 7)
        FSTEP(0xB1, 1) FSTEP(0x4E, 2) FSTEP(0xB1, 1)
#undef FSTEP
        // LN2
        float sy = hsum16d(yv[0] + yv[1] + yv[2] + yv[3]);
        float syy = hsum16d(yv[0] * yv[0] + yv[1] * yv[1] + yv[2] * yv[2] + yv[3] * yv[3]);
        float mu2 = sy * 0.015625f;
        float var2 = syy * 0.015625f - mu2 * mu2;
        float r2 = rsqrtf(var2 + 1e-5f);
        f32x4 g2r = T4[378 + u], b2r = T4[394 + u];
        f32x4 tv = (yv - mu2) * (g2r * r2) + b2r;
        // mem = sum over slots
        f32x4 mem4;
#pragma unroll
        for (int k = 0; k < 4; k++) {
            float s = tv[k];
            s += xr(s, 16);
            s += xr(s, 32);
            mem4[k] = s;
        }
        if (m == 0) *(f32x4*)(mem_out + (size_t)itu * 64 + u * 4) = mem4;
        if (isE) {
            f32x4 mg0 = T4[256 + u];
            f32x4 mg1 = T4[272 + u];
            f32x4 mg2 = T4[288 + u];
            f32x4 mg3 = T4[304 + u];
            f32x4 pcv = yv[0] * mg0 + yv[1] * mg1 + yv[2] * mg2 + yv[3] * mg3;
            f32x4 McV = T4[344];
            f32x4 CcV = T4[345];
            f32x4 dv;
            dv[0] = hsum16d(pcv[0]);
            dv[1] = hsum16d(pcv[1]);
            dv[2] = hsum16d(pcv[2]);
            dv[3] = hsum16d(pcv[3]);
            f32x4 cv = (dv - McV * mu2) * r2 + CcV;
            int row = rb + m * st;
            if (u == 0) {
                *(f32x4*)(out_cat + (size_t)row * 4) = cv;
                out_label[row] = (float)m;
            }
        }
    }
}

// ================= message bilinear via fp16 MFMA (merged edges+nodes) =================
// blocks [0,625) edges (NE = 625*256 exactly); [625,704) nodes.
// v2: ZERO LDS, ZERO barriers. W fragments are read directly from global
// (512 KB Wstg is L2-resident; each element is used once per wave, so LDS
// staging only doubled the movement and forced 32 barriers/block). The h
// transpose never crossed waves -> __shfl of dup-packed fp16 replaces hTu.
// launch_bounds(256,3): ~12 waves/CU for L2-latency cover; VGPR cap ~168.
__global__ __launch_bounds__(256, 3) void msg_kernel(
    const float* __restrict__ feat, const int* __restrict__ src, const int* __restrict__ dstv,
    const float* __restrict__ mem_all, const unsigned short* __restrict__ Wstg,
    float* __restrict__ agg, float* __restrict__ msg_n) {
    constexpr int EB = NE / 256;  // 625
    int tid = threadIdx.x;
    int w = tid >> 6, lane = tid & 63;
    int m16 = lane & 15, q = lane >> 4;
    bool isE = blockIdx.x < EB;
    int blockbase = (isE ? blockIdx.x : blockIdx.x - EB) * 256;
    int count = isE ? NE : NN;
    size_t moff = isE ? 0 : (size_t)NE;
    int wavebase = w * 64;

    // mem rows -> packed fp16 pairs
    f16x2 mpk[4][2][4];
#pragma unroll
    for (int Mt = 0; Mt < 4; Mt++) {
        int it = blockbase + wavebase + Mt * 16 + m16;
        if (!isE && it >= count) it = count - 1;
        const float* mrow = mem_all + (moff + (size_t)it) * 64;
#pragma unroll
        for (int ks = 0; ks < 2; ks++) {
            float4 a = *(const float4*)(mrow + ks * 32 + q * 8);
            float4 b = *(const float4*)(mrow + ks * 32 + q * 8 + 4);
            mpk[Mt][ks][0] = f16x2{(_Float16)a.x, (_Float16)a.y};
            mpk[Mt][ks][1] = f16x2{(_Float16)a.z, (_Float16)a.w};
            mpk[Mt][ks][2] = f16x2{(_Float16)b.x, (_Float16)b.y};
            mpk[Mt][ks][3] = f16x2{(_Float16)b.z, (_Float16)b.w};
        }
    }
    f32x4 acc[4][4];
#pragma unroll
    for (int Mt = 0; Mt < 4; Mt++)
#pragma unroll
        for (int nt = 0; nt < 4; nt++) {
            f32x4 z = {0.f, 0.f, 0.f, 0.f};
            acc[Mt][nt] = z;
        }

    // this thread's own h row (for the in-wave transpose via shfl)
    int hit = blockbase + tid;
    if (!isE && hit >= count) hit = count - 1;
    int hidx = isE ? src[hit] : hit;
    const float* hrow = feat + (size_t)hidx * 64;

    for (int ch = 0; ch < 16; ch++) {
        float4 hv = *(const float4*)(hrow + ch * 4);
        unsigned hpk[4];
        {
            union { f16x2 f; unsigned u; } cc;
            cc.f = f16x2{(_Float16)hv.x, (_Float16)hv.x}; hpk[0] = cc.u;
            cc.f = f16x2{(_Float16)hv.y, (_Float16)hv.y}; hpk[1] = cc.u;
            cc.f = f16x2{(_Float16)hv.z, (_Float16)hv.z}; hpk[2] = cc.u;
            cc.f = f16x2{(_Float16)hv.w, (_Float16)hv.w}; hpk[3] = cc.u;
        }
#pragma unroll
        for (int il = 0; il < 4; il++) {
            const unsigned short* wtile = Wstg + (size_t)(ch * 4 + il) * 4096;
            f16x8 afr[4][2];
#pragma unroll
            for (int Mt = 0; Mt < 4; Mt++) {
                union { f16x2 f; unsigned u; } hh;
                hh.u = (unsigned)__shfl((int)hpk[il], Mt * 16 + m16, 64);
                f16x2 hd = hh.f;
#pragma unroll
                for (int ks = 0; ks < 2; ks++) {
                    union { unsigned u[4]; f16x8 v; } uu;
#pragma unroll
                    for (int jj = 0; jj < 4; jj++) {
                        union { f16x2 f; unsigned u; } rr;
                        rr.f = mpk[Mt][ks][jj] * hd;   // v_pk_mul_f16
                        uu.u[jj] = rr.u;
                    }
                    afr[Mt][ks] = uu.v;
                }
            }
#pragma unroll
            for (int nt = 0; nt < 4; nt++) {
                int o = nt * 16 + m16;
#pragma unroll
                for (int ks = 0; ks < 2; ks++) {
                    union { uint4 u; f16x8 v; } bb;
                    bb.u = *(const uint4*)&wtile[o * 64 + ks * 32 + q * 8];
#pragma unroll
                    for (int Mt = 0; Mt < 4; Mt++)
                        acc[Mt][nt] = __builtin_amdgcn_mfma_f32_16x16x32_f16(
                            afr[Mt][ks], bb.v, acc[Mt][nt], 0, 0, 0);
                }
            }
        }
    }
#pragma unroll
    for (int Mt = 0; Mt < 4; Mt++) {
        int ib = blockbase + wavebase + Mt * 16 + q * 4;
        if (!isE) {
#pragma unroll
            for (int r = 0; r < 4; r++) {
                int it = ib + r;
                if (it < count) {
#pragma unroll
                    for (int nt = 0; nt < 4; nt++)
                        msg_n[(size_t)it * 64 + nt * 16 + m16] = acc[Mt][nt][r];
                }
            }
        } else {
            int4 dd = *(const int4*)(dstv + ib);
#pragma unroll
            for (int r = 0; r < 4; r++) {
                int dn = (&dd.x)[r];
#pragma unroll
                for (int nt = 0; nt < 4; nt++)
                    atomicAdd(&agg[(size_t)dn * 64 + nt * 16 + m16], acc[Mt][nt][r]);
            }
        }
    }
}

// ================= final node combine =================
__global__ __launch_bounds__(256) void final_kernel(
    const float* __restrict__ agg, const float* __restrict__ deg, const float* __restrict__ msgn,
    const float* __restrict__ lnw_g, const float* __restrict__ lnw_b,
    const float* __restrict__ h_bias, float* __restrict__ outp, int nN) {
    int tid = threadIdx.x, w = tid >> 6, l = tid & 63;
    int n = blockIdx.x * 4 + w;
    if (n >= nN) return;
    float a = agg[(size_t)n * 64 + l] / fmaxf(deg[n], 1.f);
    float mu = wsum64(a) * (1.f / 64.f);
    float d = a - mu;
    float var = wsum64(d * d) * (1.f / 64.f);
    float v = d * rsqrtf(var + 1e-5f) * lnw_g[l] + lnw_b[l] + h_bias[l] + msgn[(size_t)n * 64 + l];
    outp[(size_t)n * 64 + l] = v > 0.f ? v : 0.2f * v;
}

// ================= host =================

extern "C" void kernel_launch(void* const* d_in, const int* in_sizes, int n_in,
                              void* d_out, int out_size, void* d_ws, size_t ws_size,
                              hipStream_t stream) {
    const float* feat   = (const float*)d_in[0];
    const int*   src    = (const int*)d_in[1];
    const int*   dst    = (const int*)d_in[2];
    const int*   etype  = (const int*)d_in[3];
    const float* cls_w  = (const float*)d_in[4];
    const float* sep    = (const float*)d_in[5];
    const float* in_w   = (const float*)d_in[6];
    const float* in_b   = (const float*)d_in[7];
    const float* out_w  = (const float*)d_in[8];
    const float* out_b  = (const float*)d_in[9];
    const float* ln1_g  = (const float*)d_in[10];
    const float* ln1_b  = (const float*)d_in[11];
    const float* ln2_g  = (const float*)d_in[12];
    const float* ln2_b  = (const float*)d_in[13];
    const float* ff1_w  = (const float*)d_in[14];
    const float* ff1_b  = (const float*)d_in[15];
    const float* ff2_w  = (const float*)d_in[16];
    const float* ff2_b  = (const float*)d_in[17];
    const float* mc_w   = (const float*)d_in[18];
    const float* mc_b   = (const float*)d_in[19];
    const float* memw_w = (const float*)d_in[20];
    const float* h_bias = (const float*)d_in[21];
    const float* lnw_g  = (const float*)d_in[22];
    const float* lnw_b  = (const float*)d_in[23];

    char* ws = (char*)d_ws;
    size_t off = 0;
    auto nxt = [&](size_t bytes) -> void* {
        void* p = ws + off;
        off += (bytes + 255) & ~(size_t)255;
        return p;
    };
    unsigned short* Wstg = (unsigned short*)nxt(64 * 64 * 64 * sizeof(unsigned short));
    float* SWg     = (float*)nxt(1024 * sizeof(float));
    float* SB16    = (float*)nxt(16 * sizeof(float));
    float* OvcG    = (float*)nxt(1024 * sizeof(float));
    float* OvsG    = (float*)nxt(256 * sizeof(float));
    float* bOvG    = (float*)nxt(256 * sizeof(float));
    float* s0n     = (float*)nxt(16 * sizeof(float));
    float* s2n     = (float*)nxt(16 * sizeof(float));
    float* MC8     = (float*)nxt(8 * sizeof(float));
    float* GcT     = (float*)nxt(256 * sizeof(float));
    float* GsT     = (float*)nxt(64 * sizeof(float));
    float* DCC     = (float*)nxt(256 * sizeof(float));
    float* B0T     = (float*)nxt(256 * sizeof(float));
    float* mgT     = (float*)nxt(256 * sizeof(float));
    float* WOVg    = (float*)nxt(16384 * sizeof(float));
    float* Sg      = (float*)nxt((size_t)NN * 16 * sizeof(float));
    float* Ovg     = (float*)nxt((size_t)NN * 256 * sizeof(float));
    float* Gn      = (float*)nxt((size_t)NN * 64 * sizeof(float));
    int*   bc      = (int*)nxt(625 * 5 * sizeof(int));
    int*   rowbase = (int*)nxt((size_t)NE * sizeof(int));
    int*   estride = (int*)nxt((size_t)NE * sizeof(int));
    // mem_all: NE edge rows then NN node rows, contiguous
    float* mem_all = (float*)nxt((size_t)(NE + NN) * 64 * sizeof(float));
    float* agg     = (float*)nxt((size_t)NN * 64 * sizeof(float));
    float* deg     = (float*)nxt((size_t)NN * sizeof(float));
    float* msg_n   = (float*)nxt((size_t)NN * 64 * sizeof(float));
    (void)ws_size; (void)in_sizes; (void)n_in; (void)out_size;

    float* out_node  = (float*)d_out;
    float* out_cat   = out_node + (size_t)NN * 64;
    float* out_label = out_cat + (size_t)4 * NE * 4;

    // A: prep_w | prep_wov | precomp+prep2 | hist | zero-agg | zero-deg
    prepA_kernel<<<2984, 256, 0, stream>>>(
        memw_w, Wstg, in_w, out_w, WOVg, cls_w, sep, in_b, etype, bc, agg, deg,
        mc_w, mc_b, ln1_g, ln1_b, ln2_g, ln2_b, ff1_w, ff1_b, out_b,
        SWg, SB16, OvcG, OvsG, bOvG, s0n, s2n, MC8, GcT, GsT, DCC, B0T, mgT);
    // C: rank(self-scan)+deg | node_pre
    prepC_kernel<<<5625, 256, 0, stream>>>(etype, bc, dst, deg, rowbase, estride,
                                           feat, SWg, SB16, WOVg, bOvG, ff1_w, ln1_g,
                                           Sg, Ovg, Gn);
    // encoder (edges + nodes)
    enc_kernel<<<2048, 256, 0, stream>>>(
        src, dst, Sg, Ovg, Gn, OvcG, OvsG, GcT, GsT, DCC, B0T, mgT, s0n, s2n, MC8,
        ln1_g, ln1_b, ln2_g, ln2_b, ff2_w, ff2_b,
        rowbase, estride, mem_all, out_cat, out_label);
    // message bilinear (edges + nodes), barrier-free
    msg_kernel<<<625 + (NN + 255) / 256, 256, 0, stream>>>(
        feat, src, dst, mem_all, Wstg, agg, msg_n);

    final_kernel<<<(NN + 3) / 4, 256, 0, stream>>>(agg, deg, msg_n, lnw_g, lnw_b, h_bias, out_node, NN);
}

// Round 9
// 605.646 us; speedup vs baseline: 1.0422x; 1.0422x over previous
//
#include <hip/hip_runtime.h>

#define DI __device__ __forceinline__

static constexpr int NN = 20000;   // nodes
static constexpr int NE = 160000;  // edges

typedef __attribute__((ext_vector_type(4))) float f32x4;
typedef _Float16 f16x2 __attribute__((ext_vector_type(2)));
typedef _Float16 f16x8 __attribute__((ext_vector_type(8)));

DI float rl(float v, int lane) {
    return __int_as_float(__builtin_amdgcn_readlane(__float_as_int(v), lane));
}
DI float xr(float v, int m) { return __shfl_xor(v, m, 64); }
DI int xri(int v, int m) { return __shfl_xor(v, m, 64); }
DI float wsum64(float v) {
    v += xr(v, 1); v += xr(v, 2); v += xr(v, 4);
    v += xr(v, 8); v += xr(v, 16); v += xr(v, 32);
    return v;
}
DI int wsum64i(int v) {
    v += xri(v, 1); v += xri(v, 2); v += xri(v, 4);
    v += xri(v, 8); v += xri(v, 16); v += xri(v, 32);
    return v;
}
DI float hsum16(float v) {
    v += xr(v, 1); v += xr(v, 2); v += xr(v, 4); v += xr(v, 8);
    return v;
}
// DPP-based reductions: pure VALU, no LDS-pipe traffic.
DI float hsum16d(float v) {
    v += __int_as_float(__builtin_amdgcn_mov_dpp(__float_as_int(v), 0xB1, 0xF, 0xF, true));   // xor1
    v += __int_as_float(__builtin_amdgcn_mov_dpp(__float_as_int(v), 0x4E, 0xF, 0xF, true));   // xor2
    v += __int_as_float(__builtin_amdgcn_mov_dpp(__float_as_int(v), 0x141, 0xF, 0xF, true));  // half mirror
    v += __int_as_float(__builtin_amdgcn_mov_dpp(__float_as_int(v), 0x140, 0xF, 0xF, true));  // row mirror
    return v;
}
DI float wsum64v(float v) {
    v = hsum16d(v);
    return (rl(v, 0) + rl(v, 16)) + (rl(v, 32) + rl(v, 48));
}
DI unsigned short f2h(float x) {
    union { _Float16 f; unsigned short u; } c;
    c.f = (_Float16)x;
    return c.u;
}

// ================= prepA =================
// block ranges:
//   [0,1024)      prep_w   (memw_w -> fp16, layout [i][o][d])
//   [1024,1088)   prep_wov
//   1088          fused precomp+prep2 (P in LDS, all small tables out)
//   [1089,1714)   hist (etype block counts)
//   [1714,2964)   zero agg (float4 stores)
//   [2964,2984)   zero deg
__global__ __launch_bounds__(256) void prepA_kernel(
    const float* __restrict__ mw, unsigned short* __restrict__ Wstg,
    const float* __restrict__ in_w, const float* __restrict__ out_w,
    float* __restrict__ WOVg,
    const float* __restrict__ cls_w, const float* __restrict__ sep,
    const float* __restrict__ in_b,
    const int* __restrict__ et, int* __restrict__ bc,
    float* __restrict__ agg, float* __restrict__ deg,
    const float* __restrict__ mc_w, const float* __restrict__ mc_b,
    const float* __restrict__ ln1_g, const float* __restrict__ ln1_b,
    const float* __restrict__ ln2_g, const float* __restrict__ ln2_b,
    const float* __restrict__ ff1_w, const float* __restrict__ ff1_b,
    const float* __restrict__ out_b,
    float* __restrict__ SWg, float* __restrict__ SB16,
    float* __restrict__ OvcG, float* __restrict__ OvsG,
    float* __restrict__ bOvG, float* __restrict__ s0n,
    float* __restrict__ s2n, float* __restrict__ MC8,
    float* __restrict__ GcT, float* __restrict__ GsT,
    float* __restrict__ DCC, float* __restrict__ B0T,
    float* __restrict__ mgT) {
    int b = blockIdx.x, t = threadIdx.x;
    __shared__ int c[5];
    __shared__ float P[608];
    if (b < 1024) {                      // prep_w
        int idx = b * 256 + t;
        int d = idx & 63, o = (idx >> 6) & 63, i = idx >> 12;
        Wstg[idx] = f2h(mw[(o * 64 + i) * 64 + d]);
    } else if (b < 1088) {               // prep_wov
        int u = (b - 1024) * 256 + t;    // 16384
        int h = u & 3, l = (u >> 2) & 63, j = u >> 8;
        float acc = 0.f;
        for (int i = 0; i < 16; i++)
            acc += out_w[l * 64 + h * 16 + i] * in_w[(128 + h * 16 + i) * 64 + j];
        WOVg[u] = acc;
    } else if (b == 1088) {              // fused precomp + prep2
        if (t < 64) {                    // precomp into LDS P
            int l = t;
            float bq = in_b[l], bk = in_b[64 + l], bv = in_b[128 + l];
            float xs = sep[l];
            float ks = bk, vs = bv;
            for (int j = 0; j < 64; j++) {
                float xj = rl(xs, j);
                ks += in_w[(64 + l) * 64 + j] * xj;
                vs += in_w[(128 + l) * 64 + j] * xj;
            }
            P[512 + l] = vs;
            for (int m = 0; m < 4; m++) {
                float xc = cls_w[m * 64 + l];
                float q0 = bq, kc = bk, vc = bv;
                for (int j = 0; j < 64; j++) {
                    float xj = rl(xc, j);
                    q0 += in_w[l * 64 + j] * xj;
                    kc += in_w[(64 + l) * 64 + j] * xj;
                    vc += in_w[(128 + l) * 64 + j] * xj;
                }
                P[m * 64 + l] = q0;
                P[256 + m * 64 + l] = vc;
                float p0 = hsum16(q0 * kc);
                float p2 = hsum16(q0 * ks);
                if ((l & 15) == 0) {
                    P[576 + m * 4 + (l >> 4)] = p0 * 0.25f;
                    P[592 + m * 4 + (l >> 4)] = p2 * 0.25f;
                }
            }
        }
        __syncthreads();
        // prep2
        for (int u = t; u < 1024; u += 256) {       // SW
            int m = u >> 8, h = (u >> 6) & 3, j = u & 63;
            float acc = 0.f;
            for (int i = 0; i < 16; i++)
                acc += P[m * 64 + h * 16 + i] * in_w[(64 + h * 16 + i) * 64 + j];
            SWg[u] = 0.25f * acc;
        }
        for (int u = t; u < 1024; u += 256) {       // Ovc
            int h = u & 3, ll = (u >> 2) & 63, m = u >> 8;
            float acc = 0.f;
            for (int i = 0; i < 16; i++)
                acc += out_w[ll * 64 + h * 16 + i] * P[256 + m * 64 + h * 16 + i];
            OvcG[u] = acc;
        }
        if (t < 256) {                              // Ovs, bOv
            int h = t & 3, ll = t >> 2;
            float a1 = 0.f, a2 = 0.f;
            for (int i = 0; i < 16; i++) {
                a1 += out_w[ll * 64 + h * 16 + i] * P[512 + h * 16 + i];
                a2 += out_w[ll * 64 + h * 16 + i] * in_b[128 + h * 16 + i];
            }
            OvsG[t] = a1;
            bOvG[t] = a2;
        }
        if (t < 256) {                              // B0T, mgT
            B0T[t] = cls_w[t] + out_b[t & 63];
            int p = t >> 2, cc = t & 3;
            mgT[t] = mc_w[cc * 64 + p] * ln2_g[p];
        }
        if (t < 16) {                               // SB16, s0n, s2n
            int m = t >> 2, h = t & 3;
            float acc = 0.f;
            for (int i = 0; i < 16; i++)
                acc += P[m * 64 + h * 16 + i] * in_b[64 + h * 16 + i];
            SB16[t] = 0.25f * acc;
            s0n[t] = P[576 + t];
            s2n[t] = P[592 + t];
        }
        if (t < 8) {                                // Mc / Cc
            int cc = t & 3;
            float acc = 0.f;
            if (t < 4) {
                for (int ll = 0; ll < 64; ll++) acc += mc_w[cc * 64 + ll] * ln2_g[ll];
            } else {
                for (int ll = 0; ll < 64; ll++) acc += mc_w[cc * 64 + ll] * ln2_b[ll];
                acc += mc_b[cc];
            }
            MC8[t] = acc;
        }
        __syncthreads();   // block-level fence: OvcG/OvsG global writes visible
        if (t < 256) {                              // GcT
            int m = t >> 6, f = (t >> 2) & 15, h = t & 3;
            float acc = 0.f;
            for (int p = 0; p < 64; p++)
                acc += ff1_w[f * 64 + p] * ln1_g[p] * OvcG[(m * 64 + p) * 4 + h];
            GcT[t] = acc;
        }
        if (t < 64) {                               // GsT
            int f = t >> 2, h = t & 3;
            float acc = 0.f;
            for (int p = 0; p < 64; p++)
                acc += ff1_w[f * 64 + p] * ln1_g[p] * OvsG[p * 4 + h];
            GsT[t] = acc;
        }
        if (t < 64) {                               // DCC
            int m = t >> 4, f = t & 15;
            float d0 = 0.f, c1 = 0.f, c2 = 0.f;
            for (int p = 0; p < 64; p++) {
                float wv = ff1_w[f * 64 + p];
                d0 += wv * ln1_g[p] * (cls_w[m * 64 + p] + out_b[p]);
                c1 += wv * ln1_g[p];
                c2 += wv * ln1_b[p];
            }
            f32x4 r = {d0, c1, c2 + ff1_b[f], 0.f};
            ((f32x4*)DCC)[t] = r;
        }
    } else if (b < 1714) {               // hist
        int bb = b - 1089;
        if (t < 5) c[t] = 0;
        __syncthreads();
        int e = bb * 256 + t;
        atomicAdd(&c[et[e]], 1);
        __syncthreads();
        if (t < 5) bc[bb * 5 + t] = c[t];
    } else if (b < 2964) {               // zero agg (exact: 1250*256 f32x4)
        int idx = (b - 1714) * 256 + t;
        f32x4 z = {0.f, 0.f, 0.f, 0.f};
        ((f32x4*)agg)[idx] = z;
    } else {                             // zero deg (5000 f32x4)
        int idx = (b - 2964) * 256 + t;
        if (idx < 5000) {
            f32x4 z = {0.f, 0.f, 0.f, 0.f};
            ((f32x4*)deg)[idx] = z;
        }
    }
}

// ================= prepC: [rank(self-scan)+deg | node_pre] =================
// blocks [0,625) rank; [625,5625) node_pre
__global__ __launch_bounds__(256) void prepC_kernel(
    const int* __restrict__ et, const int* __restrict__ bc,
    const int* __restrict__ dstp, float* __restrict__ deg,
    int* __restrict__ rowbase, int* __restrict__ estride,
    const float* __restrict__ feat, const float* __restrict__ SWg,
    const float* __restrict__ SB16, const float* __restrict__ WOVg,
    const float* __restrict__ bOvG, const float* __restrict__ ff1_w,
    const float* __restrict__ ln1_g,
    float* __restrict__ Sout, float* __restrict__ Ovout, float* __restrict__ Gn) {
    __shared__ float SWs[1024];
    __shared__ f32x4 WOVs[4096];
    __shared__ __align__(16) float F1gL[1024];
    __shared__ __align__(16) float accT[4][4][64];
    __shared__ int wc[4][5];
    __shared__ int pre_s[5], tot_s[5], cs5[5];
    int tid = threadIdx.x;
    if (blockIdx.x < 625) {              // rank with self-scan + deg
        int b = blockIdx.x;
        if (tid < 5) { pre_s[tid] = 0; tot_s[tid] = 0; }
        __syncthreads();
#pragma unroll
        for (int ty = 0; ty < 5; ty++) {
            int pp = 0, tt = 0;
            for (int b2 = tid; b2 < 625; b2 += 256) {
                int v = bc[b2 * 5 + ty];
                tt += v;
                if (b2 < b) pp += v;
            }
            pp = wsum64i(pp);
            tt = wsum64i(tt);
            if ((tid & 63) == 0) {
                atomicAdd(&pre_s[ty], pp);
                atomicAdd(&tot_s[ty], tt);
            }
        }
        __syncthreads();
        if (tid == 0) {
            int s = 0;
            for (int e = 0; e < 5; e++) { cs5[e] = s; s += tot_s[e]; }
        }
        int w = tid >> 6, lane = tid & 63;
        int e = b * 256 + tid;           // always < NE (625*256 exact)
        int my = et[e];
        unsigned long long bal[5];
#pragma unroll
        for (int ty = 0; ty < 5; ty++) bal[ty] = __ballot(my == ty);
        if (lane == 0) {
#pragma unroll
            for (int ty = 0; ty < 5; ty++) wc[w][ty] = __popcll(bal[ty]);
        }
        __syncthreads();
        unsigned long long lt = ((unsigned long long)1 << lane) - 1;
        int intra = __popcll(bal[my] & lt);
        int pre = 0;
        for (int w2 = 0; w2 < w; w2++) pre += wc[w2][my];
        rowbase[e] = 4 * cs5[my] + pre_s[my] + pre + intra;
        estride[e] = tot_s[my];
        atomicAdd(&deg[dstp[e]], 1.0f);
        return;
    }
    // node_pre
    int nb4 = blockIdx.x - 625;
    for (int p = tid; p < 1024; p += 256) {
        SWs[p] = SWg[p];
        F1gL[p] = ff1_w[p] * ln1_g[p & 63];
    }
    for (int p = tid; p < 4096; p += 256) WOVs[p] = ((const f32x4*)WOVg)[p];
    __syncthreads();
    int w = tid >> 6, l = tid & 63;
    int n = nb4 * 4 + w;
    float f = feat[(size_t)n * 64 + l];
    f32x4 acc = ((const f32x4*)bOvG)[l];
#pragma unroll 8
    for (int j = 0; j < 64; j++) {
        float fj = rl(f, j);
        f32x4 wv = WOVs[j * 64 + l];
        acc += wv * fj;
    }
    ((f32x4*)Ovout)[(size_t)n * 64 + l] = acc;
    accT[w][0][l] = acc[0];
    accT[w][1][l] = acc[1];
    accT[w][2][l] = acc[2];
    accT[w][3][l] = acc[3];
#pragma unroll
    for (int mh = 0; mh < 16; mh++) {
        float v = SWs[mh * 64 + l] * f;
        v = wsum64v(v);
        if (l == mh) Sout[(size_t)n * 16 + mh] = v + SB16[mh];  // [m][h] layout
    }
    asm volatile("s_waitcnt lgkmcnt(0)" ::: "memory");
    int ff = l & 15, hh = l >> 4;
    float g = 0.f;
#pragma unroll
    for (int c2 = 0; c2 < 16; c2++) {
        int cc = (c2 + ff) & 15;  // stagger to avoid bank conflicts
        f32x4 wv = *(const f32x4*)&F1gL[ff * 64 + cc * 4];
        f32x4 av = *(const f32x4*)&accT[w][hh][cc * 4];
        g += wv[0] * av[0] + wv[1] * av[1] + wv[2] * av[2] + wv[3] * av[3];
    }
    Gn[(size_t)n * 64 + ff * 4 + hh] = g;
}

// ================= encoder (merged edges+nodes): slot-parallel =================
__global__ __launch_bounds__(256, 4) void enc_kernel(
    const int* __restrict__ src, const int* __restrict__ dst,
    const float* __restrict__ Sg, const float* __restrict__ Ovg,
    const float* __restrict__ Gn, const float* __restrict__ OvcG,
    const float* __restrict__ OvsG, const float* __restrict__ GcT,
    const float* __restrict__ GsT, const float* __restrict__ DCC,
    const float* __restrict__ B0T, const float* __restrict__ mgT,
    const float* __restrict__ s0n, const float* __restrict__ s2n,
    const float* __restrict__ MC8,
    const float* __restrict__ ln1_g, const float* __restrict__ ln1_b,
    const float* __restrict__ ln2_g, const float* __restrict__ ln2_b,
    const float* __restrict__ ff2_w, const float* __restrict__ ff2_b,
    const int* __restrict__ rowbase, const int* __restrict__ estride,
    float* __restrict__ mem_out, float* __restrict__ out_cat,
    float* __restrict__ out_label) {
    __shared__ __align__(16) float F2C[1024];   // F2C[f][p] = ff2_w[p][f]
    __shared__ __align__(16) float TBL[1704];   // 426 f32x4 of fused tables
    int tid = threadIdx.x;
    for (int p = tid; p < 1024; p += 256) F2C[(p & 15) * 64 + (p >> 4)] = ff2_w[p];
    {
        f32x4* T4w = (f32x4*)TBL;
        int i = tid;
        if (i < 64) {
            T4w[i]        = ((const f32x4*)B0T)[i];                         // [l]
            T4w[64 + i]   = ((const f32x4*)GcT)[i];                         // [l]
            T4w[128 + i]  = ((const f32x4*)DCC)[i];                         // [l]
            T4w[192 + (i & 3) * 16 + (i >> 2)] = ((const f32x4*)OvsG)[i];   // [k][u]
            T4w[256 + (i & 3) * 16 + (i >> 2)] = ((const f32x4*)mgT)[i];    // [k][u]
        }
        if (i < 16) {
            T4w[320 + i] = ((const f32x4*)GsT)[i];                          // [u]
            T4w[346 + i] = *(const f32x4*)(ln1_g + i * 4);                  // [u]
            T4w[362 + i] = *(const f32x4*)(ln1_b + i * 4);                  // [u]
            T4w[378 + i] = *(const f32x4*)(ln2_g + i * 4);                  // [u]
            T4w[394 + i] = *(const f32x4*)(ln2_b + i * 4);                  // [u]
            T4w[410 + i] = *(const f32x4*)(ff2_b + i * 4);                  // [u]
        }
        if (i < 4) {
            T4w[336 + i] = ((const f32x4*)s0n)[i];                          // [m]
            T4w[340 + i] = ((const f32x4*)s2n)[i];                          // [m]
        }
        if (i < 2) T4w[344 + i] = ((const f32x4*)MC8)[i];                   // Mc, Cc
    }
    __syncthreads();
    const f32x4* F2C4 = (const f32x4*)F2C;
    const f32x4* Sg4 = (const f32x4*)Sg;
    const f32x4* Og4 = (const f32x4*)Ovg;
    const f32x4* Gn4 = (const f32x4*)Gn;

    int l = tid & 63, m = l >> 4, u = l & 15;
    f32x4 OvcR0 = ((const f32x4*)OvcG)[m * 64 + u * 4 + 0];
    f32x4 OvcR1 = ((const f32x4*)OvcG)[m * 64 + u * 4 + 1];
    f32x4 OvcR2 = ((const f32x4*)OvcG)[m * 64 + u * 4 + 2];
    f32x4 OvcR3 = ((const f32x4*)OvcG)[m * 64 + u * 4 + 3];
    int ubase = u * 17;  // F2C f32x4 index for f=u, chunk=u
    int wid = blockIdx.x * 4 + (tid >> 6);
    int nw = gridDim.x * 4;

#pragma unroll 2
    for (int it = wid; it < NE + NN; it += nw) {
        int tb = 0;
        asm volatile("" : "+v"(tb));  // opaque zero: blocks LICM of LDS table reads
        const f32x4* T4 = ((const f32x4*)TBL) + tb;
        int itu = __builtin_amdgcn_readfirstlane(it);
        bool isE = itu < NE;
        int ia = isE ? src[itu] : (itu - NE);
        f32x4 SaV = Sg4[(size_t)ia * 4 + m];
        f32x4 GaV = Gn4[(size_t)ia * 16 + u];
        f32x4 OvaR0 = Og4[(size_t)ia * 64 + u * 4 + 0];
        f32x4 OvaR1 = Og4[(size_t)ia * 64 + u * 4 + 1];
        f32x4 OvaR2 = Og4[(size_t)ia * 64 + u * 4 + 2];
        f32x4 OvaR3 = Og4[(size_t)ia * 64 + u * 4 + 3];
        f32x4 SbV = SaV, GbV = GaV;
        f32x4 OvbR0 = OvaR0, OvbR1 = OvaR1, OvbR2 = OvaR2, OvbR3 = OvaR3;
        int rb = 0, st = 0;
        if (isE) {
            int ib = dst[itu];
            SbV = Sg4[(size_t)ib * 4 + m];
            GbV = Gn4[(size_t)ib * 16 + u];
            OvbR0 = Og4[(size_t)ib * 64 + u * 4 + 0];
            OvbR1 = Og4[(size_t)ib * 64 + u * 4 + 1];
            OvbR2 = Og4[(size_t)ib * 64 + u * 4 + 2];
            OvbR3 = Og4[(size_t)ib * 64 + u * 4 + 3];
            rb = rowbase[itu];
            st = estride[itu];
        }
        f32x4 s0v = T4[336 + m];
        f32x4 s2v = T4[340 + m];
        f32x4 B0v = T4[l];
        f32x4 GcV = T4[64 + l];
        f32x4 DCv = T4[128 + l];
        f32x4 GsV = T4[320 + u];
        f32x4 OvsR0 = T4[192 + u];
        f32x4 OvsR1 = T4[208 + u];
        f32x4 OvsR2 = T4[224 + u];
        f32x4 OvsR3 = T4[240 + u];

        // softmax over 4 tokens for all 4 heads
        f32x4 mx, e0, e1, e2, e3, w0v, w1v, w2v, w3v;
#pragma unroll
        for (int h = 0; h < 4; h++)
            mx[h] = fmaxf(fmaxf(s0v[h], SaV[h]), fmaxf(s2v[h], SbV[h]));
#pragma unroll
        for (int h = 0; h < 4; h++) {
            e0[h] = __expf(s0v[h] - mx[h]);
            e1[h] = __expf(SaV[h] - mx[h]);
            e2[h] = __expf(s2v[h] - mx[h]);
            e3[h] = __expf(SbV[h] - mx[h]);
        }
#pragma unroll
        for (int h = 0; h < 4; h++) {
            float inv = 1.f / (e0[h] + e1[h] + e2[h] + e3[h]);
            w0v[h] = e0[h] * inv; w1v[h] = e1[h] * inv;
            w2v[h] = e2[h] * inv; w3v[h] = e3[h] * inv;
        }
        // x build
        f32x4 xv = B0v;
#pragma unroll
        for (int h = 0; h < 4; h++) {
            float W0 = w0v[h], W1 = w1v[h], W2 = w2v[h], W3 = w3v[h];
            xv[0] += W0 * OvcR0[h] + W1 * OvaR0[h] + W2 * OvsR0[h] + W3 * OvbR0[h];
            xv[1] += W0 * OvcR1[h] + W1 * OvaR1[h] + W2 * OvsR1[h] + W3 * OvbR1[h];
            xv[2] += W0 * OvcR2[h] + W1 * OvaR2[h] + W2 * OvsR2[h] + W3 * OvbR2[h];
            xv[3] += W0 * OvcR3[h] + W1 * OvaR3[h] + W2 * OvsR3[h] + W3 * OvbR3[h];
        }
        // LN1 stats
        float sx = hsum16d(xv[0] + xv[1] + xv[2] + xv[3]);
        float sxx = hsum16d(xv[0] * xv[0] + xv[1] * xv[1] + xv[2] * xv[2] + xv[3] * xv[3]);
        float mu = sx * 0.015625f;
        float var = sxx * 0.015625f - mu * mu;
        float r1 = rsqrtf(var + 1e-5f);
        // FF1 via G-tables
        f32x4 av = w0v * GcV + w1v * GaV + w2v * GsV + w3v * GbV;
        float accF = av[0] + av[1] + av[2] + av[3] + DCv[0];
        float hp = r1 * accF - (r1 * mu) * DCv[1] + DCv[2];
        float hr = fmaxf(hp, 0.f);
        // LN1 apply, y = x1 + ff2_bias
        f32x4 g1r = T4[346 + u], b1r = T4[362 + u], f2br = T4[410 + u];
        xv = (xv - mu) * (g1r * r1) + b1r;
        f32x4 yv = xv + f2br;
        // FF2 gray-code XOR walk
        float hrot = hr;
        int a16 = ubase + tb;
        { f32x4 wv = F2C4[a16]; yv += wv * hrot; }
#define FSTEP(CTL, MSK)                                                                         \
        hrot = __int_as_float(__builtin_amdgcn_mov_dpp(__float_as_int(hrot), (CTL), 0xF, 0xF, true)); \
        a16 ^= (MSK) * 16;                                                                      \
        { f32x4 wv = F2C4[a16]; yv += wv * hrot; }
        FSTEP(0xB1, 1) FSTEP(0x4E, 2) FSTEP(0xB1, 1) FSTEP(0x141, 7)
        FSTEP(0xB1, 1) FSTEP(0x4E, 2) FSTEP(0xB1, 1) FSTEP(0x140, 15)
        FSTEP(0xB1, 1) FSTEP(0x4E, 2) FSTEP(0xB1, 1) FSTEP(0x141, 7)
        FSTEP(0xB1, 1) FSTEP(0x4E, 2) FSTEP(0xB1, 1)
#undef FSTEP
        // LN2
        float sy = hsum16d(yv[0] + yv[1] + yv[2] + yv[3]);
        float syy = hsum16d(yv[0] * yv[0] + yv[1] * yv[1] + yv[2] * yv[2] + yv[3] * yv[3]);
        float mu2 = sy * 0.015625f;
        float var2 = syy * 0.015625f - mu2 * mu2;
        float r2 = rsqrtf(var2 + 1e-5f);
        f32x4 g2r = T4[378 + u], b2r = T4[394 + u];
        f32x4 tv = (yv - mu2) * (g2r * r2) + b2r;
        // mem = sum over slots
        f32x4 mem4;
#pragma unroll
        for (int k = 0; k < 4; k++) {
            float s = tv[k];
            s += xr(s, 16);
            s += xr(s, 32);
            mem4[k] = s;
        }
        if (m == 0) *(f32x4*)(mem_out + (size_t)itu * 64 + u * 4) = mem4;
        if (isE) {
            f32x4 mg0 = T4[256 + u];
            f32x4 mg1 = T4[272 + u];
            f32x4 mg2 = T4[288 + u];
            f32x4 mg3 = T4[304 + u];
            f32x4 pcv = yv[0] * mg0 + yv[1] * mg1 + yv[2] * mg2 + yv[3] * mg3;
            f32x4 McV = T4[344];
            f32x4 CcV = T4[345];
            f32x4 dv;
            dv[0] = hsum16d(pcv[0]);
            dv[1] = hsum16d(pcv[1]);
            dv[2] = hsum16d(pcv[2]);
            dv[3] = hsum16d(pcv[3]);
            f32x4 cv = (dv - McV * mu2) * r2 + CcV;
            int row = rb + m * st;
            if (u == 0) {
                *(f32x4*)(out_cat + (size_t)row * 4) = cv;
                out_label[row] = (float)m;
            }
        }
    }
}

// ================= message bilinear via fp16 MFMA (merged edges+nodes) =================
// blocks [0,625) edges (NE = 625*256 exactly); [625,704) nodes.
// v3 = R5 LDS-staged W (RS=72, conflict-free ds_read_b128) + shfl-based h
// transpose (no hT LDS) + T14 async-split staging: issue next-ch W loads at
// the top of the iteration, compute current ch from LDS, write the landed
// registers after the read-barrier. The L2 latency of the stage hides under
// ~128 MFMAs instead of stalling between back-to-back barriers (R8 showed
// msg is latency-bound: MfmaUtil 15.8%, VALU 10%, HBM 6%).
__global__ __launch_bounds__(256, 2) void msg_kernel(
    const float* __restrict__ feat, const int* __restrict__ src, const int* __restrict__ dstv,
    const float* __restrict__ mem_all, const unsigned short* __restrict__ Wstg,
    float* __restrict__ agg, float* __restrict__ msg_n) {
    constexpr int RS = 72;
    constexpr int EB = NE / 256;  // 625
    __shared__ __align__(16) unsigned short Wt[4 * 64 * RS];   // 36864 B
    int tid = threadIdx.x;
    int w = tid >> 6, lane = tid & 63;
    int m16 = lane & 15, q = lane >> 4;
    bool isE = blockIdx.x < EB;
    int blockbase = (isE ? blockIdx.x : blockIdx.x - EB) * 256;
    int count = isE ? NE : NN;
    size_t moff = isE ? 0 : (size_t)NE;
    int wavebase = w * 64;

    // mem rows -> packed fp16 pairs
    f16x2 mpk[4][2][4];
#pragma unroll
    for (int Mt = 0; Mt < 4; Mt++) {
        int it = blockbase + wavebase + Mt * 16 + m16;
        if (!isE && it >= count) it = count - 1;
        const float* mrow = mem_all + (moff + (size_t)it) * 64;
#pragma unroll
        for (int ks = 0; ks < 2; ks++) {
            float4 a = *(const float4*)(mrow + ks * 32 + q * 8);
            float4 b = *(const float4*)(mrow + ks * 32 + q * 8 + 4);
            mpk[Mt][ks][0] = f16x2{(_Float16)a.x, (_Float16)a.y};
            mpk[Mt][ks][1] = f16x2{(_Float16)a.z, (_Float16)a.w};
            mpk[Mt][ks][2] = f16x2{(_Float16)b.x, (_Float16)b.y};
            mpk[Mt][ks][3] = f16x2{(_Float16)b.z, (_Float16)b.w};
        }
    }
    f32x4 acc[4][4];
#pragma unroll
    for (int Mt = 0; Mt < 4; Mt++)
#pragma unroll
        for (int nt = 0; nt < 4; nt++) {
            f32x4 z = {0.f, 0.f, 0.f, 0.f};
            acc[Mt][nt] = z;
        }

    // this thread's own h row (for the in-wave transpose via shfl)
    int hit = blockbase + tid;
    if (!isE && hit >= count) hit = count - 1;
    int hidx = isE ? src[hit] : hit;
    const float* hrow = feat + (size_t)hidx * 64;

    // prologue: stage ch=0
    uint4 stg[8];
#pragma unroll
    for (int p = 0; p < 8; p++)
        stg[p] = *(const uint4*)(Wstg + p * 2048 + tid * 8);
#pragma unroll
    for (int p = 0; p < 8; p++) {
        int flat = p * 2048 + tid * 8;
        int ic = flat >> 12, o = (flat >> 6) & 63, d = flat & 63;
        *(uint4*)&Wt[(ic * 64 + o) * RS + d] = stg[p];
    }
    __syncthreads();

    for (int ch = 0; ch < 16; ch++) {
        // issue next-ch W loads early (land during compute below)
        if (ch < 15) {
            const unsigned short* gsl = Wstg + (size_t)(ch + 1) * 16384;
#pragma unroll
            for (int p = 0; p < 8; p++)
                stg[p] = *(const uint4*)(gsl + p * 2048 + tid * 8);
        }
        float4 hv = *(const float4*)(hrow + ch * 4);
        unsigned hpk[4];
        {
            union { f16x2 f; unsigned u; } cc;
            cc.f = f16x2{(_Float16)hv.x, (_Float16)hv.x}; hpk[0] = cc.u;
            cc.f = f16x2{(_Float16)hv.y, (_Float16)hv.y}; hpk[1] = cc.u;
            cc.f = f16x2{(_Float16)hv.z, (_Float16)hv.z}; hpk[2] = cc.u;
            cc.f = f16x2{(_Float16)hv.w, (_Float16)hv.w}; hpk[3] = cc.u;
        }
#pragma unroll
        for (int il = 0; il < 4; il++) {
            f16x8 afr[4][2];
#pragma unroll
            for (int Mt = 0; Mt < 4; Mt++) {
                union { f16x2 f; unsigned u; } hh;
                hh.u = (unsigned)__shfl((int)hpk[il], Mt * 16 + m16, 64);
                f16x2 hd = hh.f;
#pragma unroll
                for (int ks = 0; ks < 2; ks++) {
                    union { unsigned u[4]; f16x8 v; } uu;
#pragma unroll
                    for (int jj = 0; jj < 4; jj++) {
                        union { f16x2 f; unsigned u; } rr;
                        rr.f = mpk[Mt][ks][jj] * hd;   // v_pk_mul_f16
                        uu.u[jj] = rr.u;
                    }
                    afr[Mt][ks] = uu.v;
                }
            }
            const unsigned short* wrow = &Wt[(il * 64) * RS];
#pragma unroll
            for (int nt = 0; nt < 4; nt++) {
                int o = nt * 16 + m16;
#pragma unroll
                for (int ks = 0; ks < 2; ks++) {
                    union { uint4 u; f16x8 v; } bb;
                    bb.u = *(const uint4*)&wrow[o * RS + ks * 32 + q * 8];
#pragma unroll
                    for (int Mt = 0; Mt < 4; Mt++)
                        acc[Mt][nt] = __builtin_amdgcn_mfma_f32_16x16x32_f16(
                            afr[Mt][ks], bb.v, acc[Mt][nt], 0, 0, 0);
                }
            }
        }
        __syncthreads();            // all Wt reads of this ch complete
        if (ch < 15) {
#pragma unroll
            for (int p = 0; p < 8; p++) {
                int flat = p * 2048 + tid * 8;
                int ic = flat >> 12, o = (flat >> 6) & 63, d = flat & 63;
                *(uint4*)&Wt[(ic * 64 + o) * RS + d] = stg[p];
            }
            __syncthreads();        // staged writes visible
        }
    }
#pragma unroll
    for (int Mt = 0; Mt < 4; Mt++) {
        int ib = blockbase + wavebase + Mt * 16 + q * 4;
        if (!isE) {
#pragma unroll
            for (int r = 0; r < 4; r++) {
                int it = ib + r;
                if (it < count) {
#pragma unroll
                    for (int nt = 0; nt < 4; nt++)
                        msg_n[(size_t)it * 64 + nt * 16 + m16] = acc[Mt][nt][r];
                }
            }
        } else {
            int4 dd = *(const int4*)(dstv + ib);
#pragma unroll
            for (int r = 0; r < 4; r++) {
                int dn = (&dd.x)[r];
#pragma unroll
                for (int nt = 0; nt < 4; nt++)
                    atomicAdd(&agg[(size_t)dn * 64 + nt * 16 + m16], acc[Mt][nt][r]);
            }
        }
    }
}

// ================= final node combine =================
__global__ __launch_bounds__(256) void final_kernel(
    const float* __restrict__ agg, const float* __restrict__ deg, const float* __restrict__ msgn,
    const float* __restrict__ lnw_g, const float* __restrict__ lnw_b,
    const float* __restrict__ h_bias, float* __restrict__ outp, int nN) {
    int tid = threadIdx.x, w = tid >> 6, l = tid & 63;
    int n = blockIdx.x * 4 + w;
    if (n >= nN) return;
    float a = agg[(size_t)n * 64 + l] / fmaxf(deg[n], 1.f);
    float mu = wsum64(a) * (1.f / 64.f);
    float d = a - mu;
    float var = wsum64(d * d) * (1.f / 64.f);
    float v = d * rsqrtf(var + 1e-5f) * lnw_g[l] + lnw_b[l] + h_bias[l] + msgn[(size_t)n * 64 + l];
    outp[(size_t)n * 64 + l] = v > 0.f ? v : 0.2f * v;
}

// ================= host =================

extern "C" void kernel_launch(void* const* d_in, const int* in_sizes, int n_in,
                              void* d_out, int out_size, void* d_ws, size_t ws_size,
                              hipStream_t stream) {
    const float* feat   = (const float*)d_in[0];
    const int*   src    = (const int*)d_in[1];
    const int*   dst    = (const int*)d_in[2];
    const int*   etype  = (const int*)d_in[3];
    const float* cls_w  = (const float*)d_in[4];
    const float* sep    = (const float*)d_in[5];
    const float* in_w   = (const float*)d_in[6];
    const float* in_b   = (const float*)d_in[7];
    const float* out_w  = (const float*)d_in[8];
    const float* out_b  = (const float*)d_in[9];
    const float* ln1_g  = (const float*)d_in[10];
    const float* ln1_b  = (const float*)d_in[11];
    const float* ln2_g  = (const float*)d_in[12];
    const float* ln2_b  = (const float*)d_in[13];
    const float* ff1_w  = (const float*)d_in[14];
    const float* ff1_b  = (const float*)d_in[15];
    const float* ff2_w  = (const float*)d_in[16];
    const float* ff2_b  = (const float*)d_in[17];
    const float* mc_w   = (const float*)d_in[18];
    const float* mc_b   = (const float*)d_in[19];
    const float* memw_w = (const float*)d_in[20];
    const float* h_bias = (const float*)d_in[21];
    const float* lnw_g  = (const float*)d_in[22];
    const float* lnw_b  = (const float*)d_in[23];

    char* ws = (char*)d_ws;
    size_t off = 0;
    auto nxt = [&](size_t bytes) -> void* {
        void* p = ws + off;
        off += (bytes + 255) & ~(size_t)255;
        return p;
    };
    unsigned short* Wstg = (unsigned short*)nxt(64 * 64 * 64 * sizeof(unsigned short));
    float* SWg     = (float*)nxt(1024 * sizeof(float));
    float* SB16    = (float*)nxt(16 * sizeof(float));
    float* OvcG    = (float*)nxt(1024 * sizeof(float));
    float* OvsG    = (float*)nxt(256 * sizeof(float));
    float* bOvG    = (float*)nxt(256 * sizeof(float));
    float* s0n     = (float*)nxt(16 * sizeof(float));
    float* s2n     = (float*)nxt(16 * sizeof(float));
    float* MC8     = (float*)nxt(8 * sizeof(float));
    float* GcT     = (float*)nxt(256 * sizeof(float));
    float* GsT     = (float*)nxt(64 * sizeof(float));
    float* DCC     = (float*)nxt(256 * sizeof(float));
    float* B0T     = (float*)nxt(256 * sizeof(float));
    float* mgT     = (float*)nxt(256 * sizeof(float));
    float* WOVg    = (float*)nxt(16384 * sizeof(float));
    float* Sg      = (float*)nxt((size_t)NN * 16 * sizeof(float));
    float* Ovg     = (float*)nxt((size_t)NN * 256 * sizeof(float));
    float* Gn      = (float*)nxt((size_t)NN * 64 * sizeof(float));
    int*   bc      = (int*)nxt(625 * 5 * sizeof(int));
    int*   rowbase = (int*)nxt((size_t)NE * sizeof(int));
    int*   estride = (int*)nxt((size_t)NE * sizeof(int));
    // mem_all: NE edge rows then NN node rows, contiguous
    float* mem_all = (float*)nxt((size_t)(NE + NN) * 64 * sizeof(float));
    float* agg     = (float*)nxt((size_t)NN * 64 * sizeof(float));
    float* deg     = (float*)nxt((size_t)NN * sizeof(float));
    float* msg_n   = (float*)nxt((size_t)NN * 64 * sizeof(float));
    (void)ws_size; (void)in_sizes; (void)n_in; (void)out_size;

    float* out_node  = (float*)d_out;
    float* out_cat   = out_node + (size_t)NN * 64;
    float* out_label = out_cat + (size_t)4 * NE * 4;

    // A: prep_w | prep_wov | precomp+prep2 | hist | zero-agg | zero-deg
    prepA_kernel<<<2984, 256, 0, stream>>>(
        memw_w, Wstg, in_w, out_w, WOVg, cls_w, sep, in_b, etype, bc, agg, deg,
        mc_w, mc_b, ln1_g, ln1_b, ln2_g, ln2_b, ff1_w, ff1_b, out_b,
        SWg, SB16, OvcG, OvsG, bOvG, s0n, s2n, MC8, GcT, GsT, DCC, B0T, mgT);
    // C: rank(self-scan)+deg | node_pre
    prepC_kernel<<<5625, 256, 0, stream>>>(etype, bc, dst, deg, rowbase, estride,
                                           feat, SWg, SB16, WOVg, bOvG, ff1_w, ln1_g,
                                           Sg, Ovg, Gn);
    // encoder (edges + nodes)
    enc_kernel<<<2048, 256, 0, stream>>>(
        src, dst, Sg, Ovg, Gn, OvcG, OvsG, GcT, GsT, DCC, B0T, mgT, s0n, s2n, MC8,
        ln1_g, ln1_b, ln2_g, ln2_b, ff2_w, ff2_b,
        rowbase, estride, mem_all, out_cat, out_label);
    // message bilinear (edges + nodes), LDS-staged + async-split
    msg_kernel<<<625 + (NN + 255) / 256, 256, 0, stream>>>(
        feat, src, dst, mem_all, Wstg, agg, msg_n);

    final_kernel<<<(NN + 3) / 4, 256, 0, stream>>>(agg, deg, msg_n, lnw_g, lnw_b, h_bias, out_node, NN);
}

// Round 10
// 502.916 us; speedup vs baseline: 1.2551x; 1.2043x over previous
//
#include <hip/hip_runtime.h>

#define DI __device__ __forceinline__

static constexpr int NN = 20000;   // nodes
static constexpr int NE = 160000;  // edges

typedef __attribute__((ext_vector_type(4))) float f32x4;
typedef _Float16 f16x2 __attribute__((ext_vector_type(2)));
typedef _Float16 f16x8 __attribute__((ext_vector_type(8)));

DI float rl(float v, int lane) {
    return __int_as_float(__builtin_amdgcn_readlane(__float_as_int(v), lane));
}
DI float xr(float v, int m) { return __shfl_xor(v, m, 64); }
DI int xri(int v, int m) { return __shfl_xor(v, m, 64); }
DI float wsum64(float v) {
    v += xr(v, 1); v += xr(v, 2); v += xr(v, 4);
    v += xr(v, 8); v += xr(v, 16); v += xr(v, 32);
    return v;
}
DI int wsum64i(int v) {
    v += xri(v, 1); v += xri(v, 2); v += xri(v, 4);
    v += xri(v, 8); v += xri(v, 16); v += xri(v, 32);
    return v;
}
DI float hsum16(float v) {
    v += xr(v, 1); v += xr(v, 2); v += xr(v, 4); v += xr(v, 8);
    return v;
}
// DPP-based reductions: pure VALU, no LDS-pipe traffic.
DI float hsum16d(float v) {
    v += __int_as_float(__builtin_amdgcn_mov_dpp(__float_as_int(v), 0xB1, 0xF, 0xF, true));   // xor1
    v += __int_as_float(__builtin_amdgcn_mov_dpp(__float_as_int(v), 0x4E, 0xF, 0xF, true));   // xor2
    v += __int_as_float(__builtin_amdgcn_mov_dpp(__float_as_int(v), 0x141, 0xF, 0xF, true));  // half mirror
    v += __int_as_float(__builtin_amdgcn_mov_dpp(__float_as_int(v), 0x140, 0xF, 0xF, true));  // row mirror
    return v;
}
DI float wsum64v(float v) {
    v = hsum16d(v);
    return (rl(v, 0) + rl(v, 16)) + (rl(v, 32) + rl(v, 48));
}
DI unsigned short f2h(float x) {
    union { _Float16 f; unsigned short u; } c;
    c.f = (_Float16)x;
    return c.u;
}

// ================= prepA =================
// block ranges:
//   [0,1024)      prep_w   (memw_w -> fp16, layout [i][o][d])
//   [1024,1088)   prep_wov
//   1088          fused precomp+prep2 (P in LDS, all small tables out)
//   [1089,1714)   hist (etype block counts)
//   [1714,2964)   zero agg (float4 stores)
//   [2964,2984)   zero deg
__global__ __launch_bounds__(256) void prepA_kernel(
    const float* __restrict__ mw, unsigned short* __restrict__ Wstg,
    const float* __restrict__ in_w, const float* __restrict__ out_w,
    float* __restrict__ WOVg,
    const float* __restrict__ cls_w, const float* __restrict__ sep,
    const float* __restrict__ in_b,
    const int* __restrict__ et, int* __restrict__ bc,
    float* __restrict__ agg, float* __restrict__ deg,
    const float* __restrict__ mc_w, const float* __restrict__ mc_b,
    const float* __restrict__ ln1_g, const float* __restrict__ ln1_b,
    const float* __restrict__ ln2_g, const float* __restrict__ ln2_b,
    const float* __restrict__ ff1_w, const float* __restrict__ ff1_b,
    const float* __restrict__ out_b,
    float* __restrict__ SWg, float* __restrict__ SB16,
    float* __restrict__ OvcG, float* __restrict__ OvsG,
    float* __restrict__ bOvG, float* __restrict__ s0n,
    float* __restrict__ s2n, float* __restrict__ MC8,
    float* __restrict__ GcT, float* __restrict__ GsT,
    float* __restrict__ DCC, float* __restrict__ B0T,
    float* __restrict__ mgT) {
    int b = blockIdx.x, t = threadIdx.x;
    __shared__ int c[5];
    __shared__ float P[608];
    if (b < 1024) {                      // prep_w
        int idx = b * 256 + t;
        int d = idx & 63, o = (idx >> 6) & 63, i = idx >> 12;
        Wstg[idx] = f2h(mw[(o * 64 + i) * 64 + d]);
    } else if (b < 1088) {               // prep_wov
        int u = (b - 1024) * 256 + t;    // 16384
        int h = u & 3, l = (u >> 2) & 63, j = u >> 8;
        float acc = 0.f;
        for (int i = 0; i < 16; i++)
            acc += out_w[l * 64 + h * 16 + i] * in_w[(128 + h * 16 + i) * 64 + j];
        WOVg[u] = acc;
    } else if (b == 1088) {              // fused precomp + prep2
        if (t < 64) {                    // precomp into LDS P
            int l = t;
            float bq = in_b[l], bk = in_b[64 + l], bv = in_b[128 + l];
            float xs = sep[l];
            float ks = bk, vs = bv;
            for (int j = 0; j < 64; j++) {
                float xj = rl(xs, j);
                ks += in_w[(64 + l) * 64 + j] * xj;
                vs += in_w[(128 + l) * 64 + j] * xj;
            }
            P[512 + l] = vs;
            for (int m = 0; m < 4; m++) {
                float xc = cls_w[m * 64 + l];
                float q0 = bq, kc = bk, vc = bv;
                for (int j = 0; j < 64; j++) {
                    float xj = rl(xc, j);
                    q0 += in_w[l * 64 + j] * xj;
                    kc += in_w[(64 + l) * 64 + j] * xj;
                    vc += in_w[(128 + l) * 64 + j] * xj;
                }
                P[m * 64 + l] = q0;
                P[256 + m * 64 + l] = vc;
                float p0 = hsum16(q0 * kc);
                float p2 = hsum16(q0 * ks);
                if ((l & 15) == 0) {
                    P[576 + m * 4 + (l >> 4)] = p0 * 0.25f;
                    P[592 + m * 4 + (l >> 4)] = p2 * 0.25f;
                }
            }
        }
        __syncthreads();
        // prep2
        for (int u = t; u < 1024; u += 256) {       // SW
            int m = u >> 8, h = (u >> 6) & 3, j = u & 63;
            float acc = 0.f;
            for (int i = 0; i < 16; i++)
                acc += P[m * 64 + h * 16 + i] * in_w[(64 + h * 16 + i) * 64 + j];
            SWg[u] = 0.25f * acc;
        }
        for (int u = t; u < 1024; u += 256) {       // Ovc
            int h = u & 3, ll = (u >> 2) & 63, m = u >> 8;
            float acc = 0.f;
            for (int i = 0; i < 16; i++)
                acc += out_w[ll * 64 + h * 16 + i] * P[256 + m * 64 + h * 16 + i];
            OvcG[u] = acc;
        }
        if (t < 256) {                              // Ovs, bOv
            int h = t & 3, ll = t >> 2;
            float a1 = 0.f, a2 = 0.f;
            for (int i = 0; i < 16; i++) {
                a1 += out_w[ll * 64 + h * 16 + i] * P[512 + h * 16 + i];
                a2 += out_w[ll * 64 + h * 16 + i] * in_b[128 + h * 16 + i];
            }
            OvsG[t] = a1;
            bOvG[t] = a2;
        }
        if (t < 256) {                              // B0T, mgT
            B0T[t] = cls_w[t] + out_b[t & 63];
            int p = t >> 2, cc = t & 3;
            mgT[t] = mc_w[cc * 64 + p] * ln2_g[p];
        }
        if (t < 16) {                               // SB16, s0n, s2n
            int m = t >> 2, h = t & 3;
            float acc = 0.f;
            for (int i = 0; i < 16; i++)
                acc += P[m * 64 + h * 16 + i] * in_b[64 + h * 16 + i];
            SB16[t] = 0.25f * acc;
            s0n[t] = P[576 + t];
            s2n[t] = P[592 + t];
        }
        if (t < 8) {                                // Mc / Cc
            int cc = t & 3;
            float acc = 0.f;
            if (t < 4) {
                for (int ll = 0; ll < 64; ll++) acc += mc_w[cc * 64 + ll] * ln2_g[ll];
            } else {
                for (int ll = 0; ll < 64; ll++) acc += mc_w[cc * 64 + ll] * ln2_b[ll];
                acc += mc_b[cc];
            }
            MC8[t] = acc;
        }
        __syncthreads();   // block-level fence: OvcG/OvsG global writes visible
        if (t < 256) {                              // GcT
            int m = t >> 6, f = (t >> 2) & 15, h = t & 3;
            float acc = 0.f;
            for (int p = 0; p < 64; p++)
                acc += ff1_w[f * 64 + p] * ln1_g[p] * OvcG[(m * 64 + p) * 4 + h];
            GcT[t] = acc;
        }
        if (t < 64) {                               // GsT
            int f = t >> 2, h = t & 3;
            float acc = 0.f;
            for (int p = 0; p < 64; p++)
                acc += ff1_w[f * 64 + p] * ln1_g[p] * OvsG[p * 4 + h];
            GsT[t] = acc;
        }
        if (t < 64) {                               // DCC
            int m = t >> 4, f = t & 15;
            float d0 = 0.f, c1 = 0.f, c2 = 0.f;
            for (int p = 0; p < 64; p++) {
                float wv = ff1_w[f * 64 + p];
                d0 += wv * ln1_g[p] * (cls_w[m * 64 + p] + out_b[p]);
                c1 += wv * ln1_g[p];
                c2 += wv * ln1_b[p];
            }
            f32x4 r = {d0, c1, c2 + ff1_b[f], 0.f};
            ((f32x4*)DCC)[t] = r;
        }
    } else if (b < 1714) {               // hist
        int bb = b - 1089;
        if (t < 5) c[t] = 0;
        __syncthreads();
        int e = bb * 256 + t;
        atomicAdd(&c[et[e]], 1);
        __syncthreads();
        if (t < 5) bc[bb * 5 + t] = c[t];
    } else if (b < 2964) {               // zero agg (exact: 1250*256 f32x4)
        int idx = (b - 1714) * 256 + t;
        f32x4 z = {0.f, 0.f, 0.f, 0.f};
        ((f32x4*)agg)[idx] = z;
    } else {                             // zero deg (5000 f32x4)
        int idx = (b - 2964) * 256 + t;
        if (idx < 5000) {
            f32x4 z = {0.f, 0.f, 0.f, 0.f};
            ((f32x4*)deg)[idx] = z;
        }
    }
}

// ================= prepC: [rank(self-scan)+deg | node_pre] =================
// blocks [0,625) rank; [625,5625) node_pre
__global__ __launch_bounds__(256) void prepC_kernel(
    const int* __restrict__ et, const int* __restrict__ bc,
    const int* __restrict__ dstp, float* __restrict__ deg,
    int* __restrict__ rowbase, int* __restrict__ estride,
    const float* __restrict__ feat, const float* __restrict__ SWg,
    const float* __restrict__ SB16, const float* __restrict__ WOVg,
    const float* __restrict__ bOvG, const float* __restrict__ ff1_w,
    const float* __restrict__ ln1_g,
    float* __restrict__ Sout, float* __restrict__ Ovout, float* __restrict__ Gn) {
    __shared__ float SWs[1024];
    __shared__ f32x4 WOVs[4096];
    __shared__ __align__(16) float F1gL[1024];
    __shared__ __align__(16) float accT[4][4][64];
    __shared__ int wc[4][5];
    __shared__ int pre_s[5], tot_s[5], cs5[5];
    int tid = threadIdx.x;
    if (blockIdx.x < 625) {              // rank with self-scan + deg
        int b = blockIdx.x;
        if (tid < 5) { pre_s[tid] = 0; tot_s[tid] = 0; }
        __syncthreads();
#pragma unroll
        for (int ty = 0; ty < 5; ty++) {
            int pp = 0, tt = 0;
            for (int b2 = tid; b2 < 625; b2 += 256) {
                int v = bc[b2 * 5 + ty];
                tt += v;
                if (b2 < b) pp += v;
            }
            pp = wsum64i(pp);
            tt = wsum64i(tt);
            if ((tid & 63) == 0) {
                atomicAdd(&pre_s[ty], pp);
                atomicAdd(&tot_s[ty], tt);
            }
        }
        __syncthreads();
        if (tid == 0) {
            int s = 0;
            for (int e = 0; e < 5; e++) { cs5[e] = s; s += tot_s[e]; }
        }
        int w = tid >> 6, lane = tid & 63;
        int e = b * 256 + tid;           // always < NE (625*256 exact)
        int my = et[e];
        unsigned long long bal[5];
#pragma unroll
        for (int ty = 0; ty < 5; ty++) bal[ty] = __ballot(my == ty);
        if (lane == 0) {
#pragma unroll
            for (int ty = 0; ty < 5; ty++) wc[w][ty] = __popcll(bal[ty]);
        }
        __syncthreads();
        unsigned long long lt = ((unsigned long long)1 << lane) - 1;
        int intra = __popcll(bal[my] & lt);
        int pre = 0;
        for (int w2 = 0; w2 < w; w2++) pre += wc[w2][my];
        rowbase[e] = 4 * cs5[my] + pre_s[my] + pre + intra;
        estride[e] = tot_s[my];
        atomicAdd(&deg[dstp[e]], 1.0f);
        return;
    }
    // node_pre
    int nb4 = blockIdx.x - 625;
    for (int p = tid; p < 1024; p += 256) {
        SWs[p] = SWg[p];
        F1gL[p] = ff1_w[p] * ln1_g[p & 63];
    }
    for (int p = tid; p < 4096; p += 256) WOVs[p] = ((const f32x4*)WOVg)[p];
    __syncthreads();
    int w = tid >> 6, l = tid & 63;
    int n = nb4 * 4 + w;
    float f = feat[(size_t)n * 64 + l];
    f32x4 acc = ((const f32x4*)bOvG)[l];
#pragma unroll 8
    for (int j = 0; j < 64; j++) {
        float fj = rl(f, j);
        f32x4 wv = WOVs[j * 64 + l];
        acc += wv * fj;
    }
    ((f32x4*)Ovout)[(size_t)n * 64 + l] = acc;
    accT[w][0][l] = acc[0];
    accT[w][1][l] = acc[1];
    accT[w][2][l] = acc[2];
    accT[w][3][l] = acc[3];
#pragma unroll
    for (int mh = 0; mh < 16; mh++) {
        float v = SWs[mh * 64 + l] * f;
        v = wsum64v(v);
        if (l == mh) Sout[(size_t)n * 16 + mh] = v + SB16[mh];  // [m][h] layout
    }
    asm volatile("s_waitcnt lgkmcnt(0)" ::: "memory");
    int ff = l & 15, hh = l >> 4;
    float g = 0.f;
#pragma unroll
    for (int c2 = 0; c2 < 16; c2++) {
        int cc = (c2 + ff) & 15;  // stagger to avoid bank conflicts
        f32x4 wv = *(const f32x4*)&F1gL[ff * 64 + cc * 4];
        f32x4 av = *(const f32x4*)&accT[w][hh][cc * 4];
        g += wv[0] * av[0] + wv[1] * av[1] + wv[2] * av[2] + wv[3] * av[3];
    }
    Gn[(size_t)n * 64 + ff * 4 + hh] = g;
}

// ================= encoder (merged edges+nodes): slot-parallel =================
__global__ __launch_bounds__(256, 4) void enc_kernel(
    const int* __restrict__ src, const int* __restrict__ dst,
    const float* __restrict__ Sg, const float* __restrict__ Ovg,
    const float* __restrict__ Gn, const float* __restrict__ OvcG,
    const float* __restrict__ OvsG, const float* __restrict__ GcT,
    const float* __restrict__ GsT, const float* __restrict__ DCC,
    const float* __restrict__ B0T, const float* __restrict__ mgT,
    const float* __restrict__ s0n, const float* __restrict__ s2n,
    const float* __restrict__ MC8,
    const float* __restrict__ ln1_g, const float* __restrict__ ln1_b,
    const float* __restrict__ ln2_g, const float* __restrict__ ln2_b,
    const float* __restrict__ ff2_w, const float* __restrict__ ff2_b,
    const int* __restrict__ rowbase, const int* __restrict__ estride,
    float* __restrict__ mem_out, float* __restrict__ out_cat,
    float* __restrict__ out_label) {
    __shared__ __align__(16) float F2C[1024];   // F2C[f][p] = ff2_w[p][f]
    __shared__ __align__(16) float TBL[1704];   // 426 f32x4 of fused tables
    int tid = threadIdx.x;
    for (int p = tid; p < 1024; p += 256) F2C[(p & 15) * 64 + (p >> 4)] = ff2_w[p];
    {
        f32x4* T4w = (f32x4*)TBL;
        int i = tid;
        if (i < 64) {
            T4w[i]        = ((const f32x4*)B0T)[i];                         // [l]
            T4w[64 + i]   = ((const f32x4*)GcT)[i];                         // [l]
            T4w[128 + i]  = ((const f32x4*)DCC)[i];                         // [l]
            T4w[192 + (i & 3) * 16 + (i >> 2)] = ((const f32x4*)OvsG)[i];   // [k][u]
            T4w[256 + (i & 3) * 16 + (i >> 2)] = ((const f32x4*)mgT)[i];    // [k][u]
        }
        if (i < 16) {
            T4w[320 + i] = ((const f32x4*)GsT)[i];                          // [u]
            T4w[346 + i] = *(const f32x4*)(ln1_g + i * 4);                  // [u]
            T4w[362 + i] = *(const f32x4*)(ln1_b + i * 4);                  // [u]
            T4w[378 + i] = *(const f32x4*)(ln2_g + i * 4);                  // [u]
            T4w[394 + i] = *(const f32x4*)(ln2_b + i * 4);                  // [u]
            T4w[410 + i] = *(const f32x4*)(ff2_b + i * 4);                  // [u]
        }
        if (i < 4) {
            T4w[336 + i] = ((const f32x4*)s0n)[i];                          // [m]
            T4w[340 + i] = ((const f32x4*)s2n)[i];                          // [m]
        }
        if (i < 2) T4w[344 + i] = ((const f32x4*)MC8)[i];                   // Mc, Cc
    }
    __syncthreads();
    const f32x4* F2C4 = (const f32x4*)F2C;
    const f32x4* Sg4 = (const f32x4*)Sg;
    const f32x4* Og4 = (const f32x4*)Ovg;
    const f32x4* Gn4 = (const f32x4*)Gn;

    int l = tid & 63, m = l >> 4, u = l & 15;
    f32x4 OvcR0 = ((const f32x4*)OvcG)[m * 64 + u * 4 + 0];
    f32x4 OvcR1 = ((const f32x4*)OvcG)[m * 64 + u * 4 + 1];
    f32x4 OvcR2 = ((const f32x4*)OvcG)[m * 64 + u * 4 + 2];
    f32x4 OvcR3 = ((const f32x4*)OvcG)[m * 64 + u * 4 + 3];
    int ubase = u * 17;  // F2C f32x4 index for f=u, chunk=u
    int wid = blockIdx.x * 4 + (tid >> 6);
    int nw = gridDim.x * 4;

#pragma unroll 2
    for (int it = wid; it < NE + NN; it += nw) {
        int tb = 0;
        asm volatile("" : "+v"(tb));  // opaque zero: blocks LICM of LDS table reads
        const f32x4* T4 = ((const f32x4*)TBL) + tb;
        int itu = __builtin_amdgcn_readfirstlane(it);
        bool isE = itu < NE;
        int ia = isE ? src[itu] : (itu - NE);
        f32x4 SaV = Sg4[(size_t)ia * 4 + m];
        f32x4 GaV = Gn4[(size_t)ia * 16 + u];
        f32x4 OvaR0 = Og4[(size_t)ia * 64 + u * 4 + 0];
        f32x4 OvaR1 = Og4[(size_t)ia * 64 + u * 4 + 1];
        f32x4 OvaR2 = Og4[(size_t)ia * 64 + u * 4 + 2];
        f32x4 OvaR3 = Og4[(size_t)ia * 64 + u * 4 + 3];
        f32x4 SbV = SaV, GbV = GaV;
        f32x4 OvbR0 = OvaR0, OvbR1 = OvaR1, OvbR2 = OvaR2, OvbR3 = OvaR3;
        int rb = 0, st = 0;
        if (isE) {
            int ib = dst[itu];
            SbV = Sg4[(size_t)ib * 4 + m];
            GbV = Gn4[(size_t)ib * 16 + u];
            OvbR0 = Og4[(size_t)ib * 64 + u * 4 + 0];
            OvbR1 = Og4[(size_t)ib * 64 + u * 4 + 1];
            OvbR2 = Og4[(size_t)ib * 64 + u * 4 + 2];
            OvbR3 = Og4[(size_t)ib * 64 + u * 4 + 3];
            rb = rowbase[itu];
            st = estride[itu];
        }
        f32x4 s0v = T4[336 + m];
        f32x4 s2v = T4[340 + m];
        f32x4 B0v = T4[l];
        f32x4 GcV = T4[64 + l];
        f32x4 DCv = T4[128 + l];
        f32x4 GsV = T4[320 + u];
        f32x4 OvsR0 = T4[192 + u];
        f32x4 OvsR1 = T4[208 + u];
        f32x4 OvsR2 = T4[224 + u];
        f32x4 OvsR3 = T4[240 + u];

        // softmax over 4 tokens for all 4 heads
        f32x4 mx, e0, e1, e2, e3, w0v, w1v, w2v, w3v;
#pragma unroll
        for (int h = 0; h < 4; h++)
            mx[h] = fmaxf(fmaxf(s0v[h], SaV[h]), fmaxf(s2v[h], SbV[h]));
#pragma unroll
        for (int h = 0; h < 4; h++) {
            e0[h] = __expf(s0v[h] - mx[h]);
            e1[h] = __expf(SaV[h] - mx[h]);
            e2[h] = __expf(s2v[h] - mx[h]);
            e3[h] = __expf(SbV[h] - mx[h]);
        }
#pragma unroll
        for (int h = 0; h < 4; h++) {
            float inv = 1.f / (e0[h] + e1[h] + e2[h] + e3[h]);
            w0v[h] = e0[h] * inv; w1v[h] = e1[h] * inv;
            w2v[h] = e2[h] * inv; w3v[h] = e3[h] * inv;
        }
        // x build
        f32x4 xv = B0v;
#pragma unroll
        for (int h = 0; h < 4; h++) {
            float W0 = w0v[h], W1 = w1v[h], W2 = w2v[h], W3 = w3v[h];
            xv[0] += W0 * OvcR0[h] + W1 * OvaR0[h] + W2 * OvsR0[h] + W3 * OvbR0[h];
            xv[1] += W0 * OvcR1[h] + W1 * OvaR1[h] + W2 * OvsR1[h] + W3 * OvbR1[h];
            xv[2] += W0 * OvcR2[h] + W1 * OvaR2[h] + W2 * OvsR2[h] + W3 * OvbR2[h];
            xv[3] += W0 * OvcR3[h] + W1 * OvaR3[h] + W2 * OvsR3[h] + W3 * OvbR3[h];
        }
        // LN1 stats
        float sx = hsum16d(xv[0] + xv[1] + xv[2] + xv[3]);
        float sxx = hsum16d(xv[0] * xv[0] + xv[1] * xv[1] + xv[2] * xv[2] + xv[3] * xv[3]);
        float mu = sx * 0.015625f;
        float var = sxx * 0.015625f - mu * mu;
        float r1 = rsqrtf(var + 1e-5f);
        // FF1 via G-tables
        f32x4 av = w0v * GcV + w1v * GaV + w2v * GsV + w3v * GbV;
        float accF = av[0] + av[1] + av[2] + av[3] + DCv[0];
        float hp = r1 * accF - (r1 * mu) * DCv[1] + DCv[2];
        float hr = fmaxf(hp, 0.f);
        // LN1 apply, y = x1 + ff2_bias
        f32x4 g1r = T4[346 + u], b1r = T4[362 + u], f2br = T4[410 + u];
        xv = (xv - mu) * (g1r * r1) + b1r;
        f32x4 yv = xv + f2br;
        // FF2 gray-code XOR walk
        float hrot = hr;
        int a16 = ubase + tb;
        { f32x4 wv = F2C4[a16]; yv += wv * hrot; }
#define FSTEP(CTL, MSK)                                                                         \
        hrot = __int_as_float(__builtin_amdgcn_mov_dpp(__float_as_int(hrot), (CTL), 0xF, 0xF, true)); \
        a16 ^= (MSK) * 16;                                                                      \
        { f32x4 wv = F2C4[a16]; yv += wv * hrot; }
        FSTEP(0xB1, 1) FSTEP(0x4E, 2) FSTEP(0xB1, 1) FSTEP(0x141, 7)
        FSTEP(0xB1, 1) FSTEP(0x4E, 2) FSTEP(0xB1, 1) FSTEP(0x140, 15)
        FSTEP(0xB1, 1) FSTEP(0x4E, 2) FSTEP(0xB1, 1) FSTEP(0x141, 7)
        FSTEP(0xB1, 1) FSTEP(0x4E, 2) FSTEP(0xB1, 1)
#undef FSTEP
        // LN2
        float sy = hsum16d(yv[0] + yv[1] + yv[2] + yv[3]);
        float syy = hsum16d(yv[0] * yv[0] + yv[1] * yv[1] + yv[2] * yv[2] + yv[3] * yv[3]);
        float mu2 = sy * 0.015625f;
        float var2 = syy * 0.015625f - mu2 * mu2;
        float r2 = rsqrtf(var2 + 1e-5f);
        f32x4 g2r = T4[378 + u], b2r = T4[394 + u];
        f32x4 tv = (yv - mu2) * (g2r * r2) + b2r;
        // mem = sum over slots
        f32x4 mem4;
#pragma unroll
        for (int k = 0; k < 4; k++) {
            float s = tv[k];
            s += xr(s, 16);
            s += xr(s, 32);
            mem4[k] = s;
        }
        if (m == 0) *(f32x4*)(mem_out + (size_t)itu * 64 + u * 4) = mem4;
        if (isE) {
            f32x4 mg0 = T4[256 + u];
            f32x4 mg1 = T4[272 + u];
            f32x4 mg2 = T4[288 + u];
            f32x4 mg3 = T4[304 + u];
            f32x4 pcv = yv[0] * mg0 + yv[1] * mg1 + yv[2] * mg2 + yv[3] * mg3;
            f32x4 McV = T4[344];
            f32x4 CcV = T4[345];
            f32x4 dv;
            dv[0] = hsum16d(pcv[0]);
            dv[1] = hsum16d(pcv[1]);
            dv[2] = hsum16d(pcv[2]);
            dv[3] = hsum16d(pcv[3]);
            f32x4 cv = (dv - McV * mu2) * r2 + CcV;
            int row = rb + m * st;
            if (u == 0) {
                *(f32x4*)(out_cat + (size_t)row * 4) = cv;
                out_label[row] = (float)m;
            }
        }
    }
}

// ================= message bilinear via fp16 MFMA (merged edges+nodes) =================
// blocks [0,625) edges (NE = 625*256 exactly); [625,704) nodes.
// R5 version (session-best): LDS-staged W (RS=72, conflict-free ds_read_b128),
// hT LDS transpose, synchronous per-ch staging, atomicAdd agg.
__global__ __launch_bounds__(256, 2) void msg_kernel(
    const float* __restrict__ feat, const int* __restrict__ src, const int* __restrict__ dstv,
    const float* __restrict__ mem_all, const unsigned short* __restrict__ Wstg,
    float* __restrict__ agg, float* __restrict__ msg_n) {
    constexpr int RS = 72;
    constexpr int EB = NE / 256;  // 625
    __shared__ __align__(16) unsigned short Wt[4 * 64 * RS];
    __shared__ unsigned hTu[4 * 256];   // dup-packed fp16 h values
    int tid = threadIdx.x;
    int w = tid >> 6, lane = tid & 63;
    int m16 = lane & 15, q = lane >> 4;
    bool isE = blockIdx.x < EB;
    int blockbase = (isE ? blockIdx.x : blockIdx.x - EB) * 256;
    int count = isE ? NE : NN;
    size_t moff = isE ? 0 : (size_t)NE;
    int wavebase = w * 64;

    // mem rows -> packed fp16 pairs
    f16x2 mpk[4][2][4];
#pragma unroll
    for (int Mt = 0; Mt < 4; Mt++) {
        int it = blockbase + wavebase + Mt * 16 + m16;
        if (!isE && it >= count) it = count - 1;
        const float* mrow = mem_all + (moff + (size_t)it) * 64;
#pragma unroll
        for (int ks = 0; ks < 2; ks++) {
            float4 a = *(const float4*)(mrow + ks * 32 + q * 8);
            float4 b = *(const float4*)(mrow + ks * 32 + q * 8 + 4);
            mpk[Mt][ks][0] = f16x2{(_Float16)a.x, (_Float16)a.y};
            mpk[Mt][ks][1] = f16x2{(_Float16)a.z, (_Float16)a.w};
            mpk[Mt][ks][2] = f16x2{(_Float16)b.x, (_Float16)b.y};
            mpk[Mt][ks][3] = f16x2{(_Float16)b.z, (_Float16)b.w};
        }
    }
    f32x4 acc[4][4];
#pragma unroll
    for (int Mt = 0; Mt < 4; Mt++)
#pragma unroll
        for (int nt = 0; nt < 4; nt++) {
            f32x4 z = {0.f, 0.f, 0.f, 0.f};
            acc[Mt][nt] = z;
        }

    for (int ch = 0; ch < 16; ch++) {
        __syncthreads();
        const unsigned short* gsl = Wstg + (size_t)ch * 4 * 4096;
#pragma unroll
        for (int p = 0; p < 8; p++) {
            int flat = p * 2048 + tid * 8;
            int ic = flat >> 12, o = (flat >> 6) & 63, d = flat & 63;
            uint4 v = *(const uint4*)(gsl + flat);
            *(uint4*)&Wt[(ic * 64 + o) * RS + d] = v;
        }
        {
            int it = blockbase + tid;
            if (!isE && it >= count) it = count - 1;
            int hidx = isE ? src[it] : it;
            float4 hv = *(const float4*)(feat + (size_t)hidx * 64 + ch * 4);
            union { f16x2 f; unsigned u; } d0, d1, d2, d3;
            d0.f = f16x2{(_Float16)hv.x, (_Float16)hv.x};
            d1.f = f16x2{(_Float16)hv.y, (_Float16)hv.y};
            d2.f = f16x2{(_Float16)hv.z, (_Float16)hv.z};
            d3.f = f16x2{(_Float16)hv.w, (_Float16)hv.w};
            hTu[0 * 256 + tid] = d0.u;
            hTu[1 * 256 + tid] = d1.u;
            hTu[2 * 256 + tid] = d2.u;
            hTu[3 * 256 + tid] = d3.u;
        }
        __syncthreads();

#pragma unroll
        for (int il = 0; il < 4; il++) {
            f16x8 afr[4][2];
#pragma unroll
            for (int Mt = 0; Mt < 4; Mt++) {
                union { f16x2 f; unsigned u; } hh;
                hh.u = hTu[il * 256 + wavebase + Mt * 16 + m16];
                f16x2 hd = hh.f;
#pragma unroll
                for (int ks = 0; ks < 2; ks++) {
                    union { unsigned u[4]; f16x8 v; } uu;
#pragma unroll
                    for (int jj = 0; jj < 4; jj++) {
                        union { f16x2 f; unsigned u; } rr;
                        rr.f = mpk[Mt][ks][jj] * hd;   // v_pk_mul_f16
                        uu.u[jj] = rr.u;
                    }
                    afr[Mt][ks] = uu.v;
                }
            }
            const unsigned short* wrow = &Wt[(il * 64) * RS];
#pragma unroll
            for (int nt = 0; nt < 4; nt++) {
#pragma unroll
                for (int ks = 0; ks < 2; ks++) {
                    int o = nt * 16 + m16;
                    union { uint4 u; f16x8 v; } bb;
                    bb.u = *(const uint4*)&wrow[o * RS + ks * 32 + q * 8];
#pragma unroll
                    for (int Mt = 0; Mt < 4; Mt++)
                        acc[Mt][nt] = __builtin_amdgcn_mfma_f32_16x16x32_f16(
                            afr[Mt][ks], bb.v, acc[Mt][nt], 0, 0, 0);
                }
            }
        }
    }
#pragma unroll
    for (int Mt = 0; Mt < 4; Mt++) {
        int ib = blockbase + wavebase + Mt * 16 + q * 4;
        if (!isE) {
#pragma unroll
            for (int r = 0; r < 4; r++) {
                int it = ib + r;
                if (it < count) {
#pragma unroll
                    for (int nt = 0; nt < 4; nt++)
                        msg_n[(size_t)it * 64 + nt * 16 + m16] = acc[Mt][nt][r];
                }
            }
        } else {
            int4 dd = *(const int4*)(dstv + ib);
#pragma unroll
            for (int r = 0; r < 4; r++) {
                int dn = (&dd.x)[r];
#pragma unroll
                for (int nt = 0; nt < 4; nt++)
                    atomicAdd(&agg[(size_t)dn * 64 + nt * 16 + m16], acc[Mt][nt][r]);
            }
        }
    }
}

// ================= final node combine =================
__global__ __launch_bounds__(256) void final_kernel(
    const float* __restrict__ agg, const float* __restrict__ deg, const float* __restrict__ msgn,
    const float* __restrict__ lnw_g, const float* __restrict__ lnw_b,
    const float* __restrict__ h_bias, float* __restrict__ outp, int nN) {
    int tid = threadIdx.x, w = tid >> 6, l = tid & 63;
    int n = blockIdx.x * 4 + w;
    if (n >= nN) return;
    float a = agg[(size_t)n * 64 + l] / fmaxf(deg[n], 1.f);
    float mu = wsum64(a) * (1.f / 64.f);
    float d = a - mu;
    float var = wsum64(d * d) * (1.f / 64.f);
    float v = d * rsqrtf(var + 1e-5f) * lnw_g[l] + lnw_b[l] + h_bias[l] + msgn[(size_t)n * 64 + l];
    outp[(size_t)n * 64 + l] = v > 0.f ? v : 0.2f * v;
}

// ================= host =================

extern "C" void kernel_launch(void* const* d_in, const int* in_sizes, int n_in,
                              void* d_out, int out_size, void* d_ws, size_t ws_size,
                              hipStream_t stream) {
    const float* feat   = (const float*)d_in[0];
    const int*   src    = (const int*)d_in[1];
    const int*   dst    = (const int*)d_in[2];
    const int*   etype  = (const int*)d_in[3];
    const float* cls_w  = (const float*)d_in[4];
    const float* sep    = (const float*)d_in[5];
    const float* in_w   = (const float*)d_in[6];
    const float* in_b   = (const float*)d_in[7];
    const float* out_w  = (const float*)d_in[8];
    const float* out_b  = (const float*)d_in[9];
    const float* ln1_g  = (const float*)d_in[10];
    const float* ln1_b  = (const float*)d_in[11];
    const float* ln2_g  = (const float*)d_in[12];
    const float* ln2_b  = (const float*)d_in[13];
    const float* ff1_w  = (const float*)d_in[14];
    const float* ff1_b  = (const float*)d_in[15];
    const float* ff2_w  = (const float*)d_in[16];
    const float* ff2_b  = (const float*)d_in[17];
    const float* mc_w   = (const float*)d_in[18];
    const float* mc_b   = (const float*)d_in[19];
    const float* memw_w = (const float*)d_in[20];
    const float* h_bias = (const float*)d_in[21];
    const float* lnw_g  = (const float*)d_in[22];
    const float* lnw_b  = (const float*)d_in[23];

    char* ws = (char*)d_ws;
    size_t off = 0;
    auto nxt = [&](size_t bytes) -> void* {
        void* p = ws + off;
        off += (bytes + 255) & ~(size_t)255;
        return p;
    };
    unsigned short* Wstg = (unsigned short*)nxt(64 * 64 * 64 * sizeof(unsigned short));
    float* SWg     = (float*)nxt(1024 * sizeof(float));
    float* SB16    = (float*)nxt(16 * sizeof(float));
    float* OvcG    = (float*)nxt(1024 * sizeof(float));
    float* OvsG    = (float*)nxt(256 * sizeof(float));
    float* bOvG    = (float*)nxt(256 * sizeof(float));
    float* s0n     = (float*)nxt(16 * sizeof(float));
    float* s2n     = (float*)nxt(16 * sizeof(float));
    float* MC8     = (float*)nxt(8 * sizeof(float));
    float* GcT     = (float*)nxt(256 * sizeof(float));
    float* GsT     = (float*)nxt(64 * sizeof(float));
    float* DCC     = (float*)nxt(256 * sizeof(float));
    float* B0T     = (float*)nxt(256 * sizeof(float));
    float* mgT     = (float*)nxt(256 * sizeof(float));
    float* WOVg    = (float*)nxt(16384 * sizeof(float));
    float* Sg      = (float*)nxt((size_t)NN * 16 * sizeof(float));
    float* Ovg     = (float*)nxt((size_t)NN * 256 * sizeof(float));
    float* Gn      = (float*)nxt((size_t)NN * 64 * sizeof(float));
    int*   bc      = (int*)nxt(625 * 5 * sizeof(int));
    int*   rowbase = (int*)nxt((size_t)NE * sizeof(int));
    int*   estride = (int*)nxt((size_t)NE * sizeof(int));
    // mem_all: NE edge rows then NN node rows, contiguous
    float* mem_all = (float*)nxt((size_t)(NE + NN) * 64 * sizeof(float));
    float* agg     = (float*)nxt((size_t)NN * 64 * sizeof(float));
    float* deg     = (float*)nxt((size_t)NN * sizeof(float));
    float* msg_n   = (float*)nxt((size_t)NN * 64 * sizeof(float));
    (void)ws_size; (void)in_sizes; (void)n_in; (void)out_size;

    float* out_node  = (float*)d_out;
    float* out_cat   = out_node + (size_t)NN * 64;
    float* out_label = out_cat + (size_t)4 * NE * 4;

    // A: prep_w | prep_wov | precomp+prep2 | hist | zero-agg | zero-deg
    prepA_kernel<<<2984, 256, 0, stream>>>(
        memw_w, Wstg, in_w, out_w, WOVg, cls_w, sep, in_b, etype, bc, agg, deg,
        mc_w, mc_b, ln1_g, ln1_b, ln2_g, ln2_b, ff1_w, ff1_b, out_b,
        SWg, SB16, OvcG, OvsG, bOvG, s0n, s2n, MC8, GcT, GsT, DCC, B0T, mgT);
    // C: rank(self-scan)+deg | node_pre
    prepC_kernel<<<5625, 256, 0, stream>>>(etype, bc, dst, deg, rowbase, estride,
                                           feat, SWg, SB16, WOVg, bOvG, ff1_w, ln1_g,
                                           Sg, Ovg, Gn);
    // encoder (edges + nodes)
    enc_kernel<<<2048, 256, 0, stream>>>(
        src, dst, Sg, Ovg, Gn, OvcG, OvsG, GcT, GsT, DCC, B0T, mgT, s0n, s2n, MC8,
        ln1_g, ln1_b, ln2_g, ln2_b, ff2_w, ff2_b,
        rowbase, estride, mem_all, out_cat, out_label);
    // message bilinear (edges + nodes), LDS-staged (R5 session-best)
    msg_kernel<<<625 + (NN + 255) / 256, 256, 0, stream>>>(
        feat, src, dst, mem_all, Wstg, agg, msg_n);

    final_kernel<<<(NN + 3) / 4, 256, 0, stream>>>(agg, deg, msg_n, lnw_g, lnw_b, h_bias, out_node, NN);
}